// Round 1
// baseline (2482.301 us; speedup 1.0000x reference)
//
#include <hip/hip_runtime.h>
#include <math.h>

// ---------------- problem constants ----------------
#define SEQ_LEN 8
#define IN_DIM 2048
#define OUT_DIM 1152
#define NTUP 56
#define NSUP 25
#define NQ 200
#define WAY 5
#define SFRAMES 200     // 25*8
#define NFRAMES 1800    // 200 support + 1600 query frames
#define SROWS 1400      // 25*56  support tuples
#define QROWS 11200     // 200*56 query tuples
#define SC_STRIDE 1408  // padded scores row stride

// tuples = combinations(range(8), 3), lexicographic
__device__ __constant__ int TUP[NTUP][3] = {
{0,1,2},{0,1,3},{0,1,4},{0,1,5},{0,1,6},{0,1,7},
{0,2,3},{0,2,4},{0,2,5},{0,2,6},{0,2,7},
{0,3,4},{0,3,5},{0,3,6},{0,3,7},
{0,4,5},{0,4,6},{0,4,7},
{0,5,6},{0,5,7},
{0,6,7},
{1,2,3},{1,2,4},{1,2,5},{1,2,6},{1,2,7},
{1,3,4},{1,3,5},{1,3,6},{1,3,7},
{1,4,5},{1,4,6},{1,4,7},
{1,5,6},{1,5,7},
{1,6,7},
{2,3,4},{2,3,5},{2,3,6},{2,3,7},
{2,4,5},{2,4,6},{2,4,7},
{2,5,6},{2,5,7},
{2,6,7},
{3,4,5},{3,4,6},{3,4,7},
{3,5,6},{3,5,7},
{3,6,7},
{4,5,6},{4,5,7},
{4,6,7},
{5,6,7}};

// ---------------- workspace layout (float offsets) ----------------
#define PE_OFF   0UL
#define AP_OFF   (PE_OFF + 16384UL)           // X+PE frames [1800,2048]
#define P_OFF    (AP_OFF + 3686400UL)         // projections [1800, 2(kv), 3(j), 1152]
#define QK_OFF   (P_OFF + 12441600UL)         // [11200,1152]
#define SK_OFF   (QK_OFF + 12902400UL)        // [1400,1152]
#define QV_OFF   (SK_OFF + 1612800UL)         // [11200,1152]
#define SV_OFF   (QV_OFF + 12902400UL)        // [1400,1152]
#define SC_OFF   (SV_OFF + 1612800UL)         // scores/attn [11200,1408]
#define DIST_OFF (SC_OFF + 15769600UL)        // [5,200]

// ---------------- kernel 0: PE table + zero dist ----------------
__global__ void k_pe_init(float* __restrict__ pe, float* __restrict__ dist) {
  int b = blockIdx.x, tid = threadIdx.x;
  if (b < SEQ_LEN) {
    const float c0 = -logf(10000.0f) / (float)IN_DIM;
    for (int i = tid; i < IN_DIM / 2; i += blockDim.x) {
      float dt = expf((float)(2 * i) * c0);
      float arg = (float)b * dt;
      pe[b * IN_DIM + 2 * i]     = sinf(arg) * 0.1f;
      pe[b * IN_DIM + 2 * i + 1] = cosf(arg) * 0.1f;
    }
  } else {
    for (int i = tid; i < WAY * NQ; i += blockDim.x) dist[i] = 0.f;
  }
}

// ---------------- kernel 1: A' = X + PE (support ++ query frames) ----------------
__global__ __launch_bounds__(256) void k_add_pe(const float* __restrict__ S,
                                                const float* __restrict__ Q,
                                                const float* __restrict__ pe,
                                                float* __restrict__ AP) {
  int idx = blockIdx.x * 256 + threadIdx.x;       // float4 index, 921600 total
  if (idx >= NFRAMES * (IN_DIM / 4)) return;
  int frame = idx >> 9;                            // /512 float4 per frame
  int k4 = (idx & 511) << 2;
  int pos = frame & 7;                             // 200 % 8 == 0, so works for both
  const float* src = (frame < SFRAMES) ? (S + (size_t)frame * IN_DIM + k4)
                                       : (Q + (size_t)(frame - SFRAMES) * IN_DIM + k4);
  float4 x = *(const float4*)src;
  float4 p = *(const float4*)(pe + (size_t)pos * IN_DIM + k4);
  x.x += p.x; x.y += p.y; x.z += p.z; x.w += p.w;
  *(float4*)(AP + (size_t)frame * IN_DIM + k4) = x;
}

// ---------------- kernel 2: GEMM1  P[1800, 6912] = A'[1800,2048] @ Wbig ----------------
// column c = w*3456 + j*1152 + d ; B[k][c] = W_w[(j*2048+k)*1152 + d]
__global__ __launch_bounds__(256) void k_gemm1(const float* __restrict__ A,
                                               const float* __restrict__ Wk,
                                               const float* __restrict__ Wv,
                                               float* __restrict__ P) {
  __shared__ float As[8][128];
  __shared__ float Bs[8][128];
  int bn = blockIdx.x;            // 0..53
  int bm = blockIdx.y;            // 0..14
  int tid = threadIdx.x;
  int row0 = bm * 128, col0 = bn * 128;
  int w = col0 / 3456;
  int r = col0 - w * 3456;
  int j = r / 1152;
  int d0 = r - j * 1152;
  const float* W = (w == 0) ? Wk : Wv;
  const float* Wbase = W + (size_t)j * 2048 * 1152 + d0;

  int lr = tid >> 1, lk = (tid & 1) * 4;
  int arow = min(row0 + lr, NFRAMES - 1);
  const float* Ap = A + (size_t)arow * IN_DIM + lk;
  int bkr = tid >> 5, bd = (tid & 31) * 4;
  int tx = tid & 15, ty = tid >> 4;
  float acc[8][8] = {};

  for (int k0 = 0; k0 < IN_DIM; k0 += 8) {
    float4 a = *(const float4*)(Ap + k0);
    float4 b = *(const float4*)(Wbase + (size_t)(k0 + bkr) * OUT_DIM + bd);
    As[lk + 0][lr] = a.x; As[lk + 1][lr] = a.y; As[lk + 2][lr] = a.z; As[lk + 3][lr] = a.w;
    *(float4*)&Bs[bkr][bd] = b;
    __syncthreads();
#pragma unroll
    for (int kk = 0; kk < 8; ++kk) {
      float a8[8], b8[8];
      *(float4*)&a8[0] = *(const float4*)&As[kk][ty * 8];
      *(float4*)&a8[4] = *(const float4*)&As[kk][ty * 8 + 4];
      *(float4*)&b8[0] = *(const float4*)&Bs[kk][tx * 8];
      *(float4*)&b8[4] = *(const float4*)&Bs[kk][tx * 8 + 4];
#pragma unroll
      for (int i = 0; i < 8; ++i)
#pragma unroll
        for (int jj = 0; jj < 8; ++jj) acc[i][jj] += a8[i] * b8[jj];
    }
    __syncthreads();
  }
#pragma unroll
  for (int i = 0; i < 8; ++i) {
    int row = row0 + ty * 8 + i;
    if (row < NFRAMES) {
      float* dst = P + (size_t)row * 6912 + col0 + tx * 8;
      *(float4*)dst = make_float4(acc[i][0], acc[i][1], acc[i][2], acc[i][3]);
      *(float4*)(dst + 4) = make_float4(acc[i][4], acc[i][5], acc[i][6], acc[i][7]);
    }
  }
}

// ---------------- kernel 3: tuple combine (+bias, +LN for k-path) ----------------
__global__ __launch_bounds__(192) void k_combine(const float* __restrict__ P,
                                                 const float* __restrict__ bk,
                                                 const float* __restrict__ bv,
                                                 const float* __restrict__ g,
                                                 const float* __restrict__ bb,
                                                 float* __restrict__ SK, float* __restrict__ QK,
                                                 float* __restrict__ SV, float* __restrict__ QV) {
  int row = blockIdx.x;     // 0..12599  (first 1400 support, rest query)
  int w = blockIdx.y;       // 0 = k, 1 = v
  int tid = threadIdx.x;    // 192 threads, 6 elems each (192*6 = 1152)
  bool isq = row >= SROWS;
  int r = isq ? row - SROWS : row;
  int n = r / NTUP, t = r - n * NTUP;
  int fbase = (isq ? SFRAMES + n * SEQ_LEN : n * SEQ_LEN);
  const float* p0 = P + (size_t)(fbase + TUP[t][0]) * 6912 + w * 3456;
  const float* p1 = P + (size_t)(fbase + TUP[t][1]) * 6912 + w * 3456 + 1152;
  const float* p2 = P + (size_t)(fbase + TUP[t][2]) * 6912 + w * 3456 + 2304;
  const float* bias = w ? bv : bk;
  float v[6];
  float sum = 0.f, sq = 0.f;
#pragma unroll
  for (int i = 0; i < 6; ++i) {
    int d = tid + i * 192;
    v[i] = p0[d] + p1[d] + p2[d] + bias[d];
    sum += v[i];
    sq += v[i] * v[i];
  }
  float* outp;
  if (w == 0) outp = isq ? (QK + (size_t)r * OUT_DIM) : (SK + (size_t)r * OUT_DIM);
  else        outp = isq ? (QV + (size_t)r * OUT_DIM) : (SV + (size_t)r * OUT_DIM);
  if (w == 0) {
#pragma unroll
    for (int off = 32; off; off >>= 1) {
      sum += __shfl_down(sum, off);
      sq += __shfl_down(sq, off);
    }
    __shared__ float s1[3], s2[3];
    int wave = tid >> 6, lane = tid & 63;
    if (lane == 0) { s1[wave] = sum; s2[wave] = sq; }
    __syncthreads();
    float tot = s1[0] + s1[1] + s1[2];
    float tot2 = s2[0] + s2[1] + s2[2];
    float mean = tot * (1.f / OUT_DIM);
    float var = tot2 * (1.f / OUT_DIM) - mean * mean;
    float inv = rsqrtf(var + 1e-5f);
#pragma unroll
    for (int i = 0; i < 6; ++i) {
      int d = tid + i * 192;
      outp[d] = (v[i] - mean) * inv * g[d] + bb[d];
    }
  } else {
#pragma unroll
    for (int i = 0; i < 6; ++i) outp[tid + i * 192] = v[i];
  }
}

// ---------------- kernel 4: scores = QK @ SK^T / sqrt(D) ----------------
__global__ __launch_bounds__(256) void k_scores(const float* __restrict__ QKm,
                                                const float* __restrict__ SKm,
                                                float* __restrict__ SC) {
  __shared__ float As[8][128];
  __shared__ float Bs[8][128];
  int bn = blockIdx.x, bm = blockIdx.y, tid = threadIdx.x;
  int row0 = bm * 128, col0 = bn * 128;
  int lr = tid >> 1, lk = (tid & 1) * 4;
  const float* Ap = QKm + (size_t)min(row0 + lr, QROWS - 1) * OUT_DIM + lk;
  const float* Bp = SKm + (size_t)min(col0 + lr, SROWS - 1) * OUT_DIM + lk;
  int tx = tid & 15, ty = tid >> 4;
  float acc[8][8] = {};
  for (int k0 = 0; k0 < OUT_DIM; k0 += 8) {
    float4 a = *(const float4*)(Ap + k0);
    float4 b = *(const float4*)(Bp + k0);
    As[lk + 0][lr] = a.x; As[lk + 1][lr] = a.y; As[lk + 2][lr] = a.z; As[lk + 3][lr] = a.w;
    Bs[lk + 0][lr] = b.x; Bs[lk + 1][lr] = b.y; Bs[lk + 2][lr] = b.z; Bs[lk + 3][lr] = b.w;
    __syncthreads();
#pragma unroll
    for (int kk = 0; kk < 8; ++kk) {
      float a8[8], b8[8];
      *(float4*)&a8[0] = *(const float4*)&As[kk][ty * 8];
      *(float4*)&a8[4] = *(const float4*)&As[kk][ty * 8 + 4];
      *(float4*)&b8[0] = *(const float4*)&Bs[kk][tx * 8];
      *(float4*)&b8[4] = *(const float4*)&Bs[kk][tx * 8 + 4];
#pragma unroll
      for (int i = 0; i < 8; ++i)
#pragma unroll
        for (int jj = 0; jj < 8; ++jj) acc[i][jj] += a8[i] * b8[jj];
    }
    __syncthreads();
  }
  const float scale = 0.029462782549439483f;  // 1/sqrt(1152)
#pragma unroll
  for (int i = 0; i < 8; ++i) {
    int row = row0 + ty * 8 + i;
    if (row >= QROWS) continue;
    float* dst = SC + (size_t)row * SC_STRIDE + col0 + tx * 8;
#pragma unroll
    for (int jj = 0; jj < 8; ++jj) {
      int col = col0 + tx * 8 + jj;
      if (col < SROWS) dst[jj] = acc[i][jj] * scale;
    }
  }
}

// ---------------- kernel 5: per-class masked softmax, in place ----------------
__global__ __launch_bounds__(256) void k_softmax(float* __restrict__ SC,
                                                 const int* __restrict__ labels) {
  int row = blockIdx.x, tid = threadIdx.x;
  float* p = SC + (size_t)row * SC_STRIDE;
  __shared__ int lab[NSUP];
  __shared__ float redm[WAY][4];
  __shared__ float reds[WAY][4];
  if (tid < NSUP) lab[tid] = labels[tid];
  __syncthreads();
  float v[6];
  int lc[6];
  float m[WAY];
#pragma unroll
  for (int c = 0; c < WAY; ++c) m[c] = -INFINITY;
#pragma unroll
  for (int it = 0; it < 6; ++it) {
    int col = it * 256 + tid;
    if (col < SROWS) {
      v[it] = p[col];
      lc[it] = lab[col / NTUP];
      m[lc[it]] = fmaxf(m[lc[it]], v[it]);
    } else lc[it] = -1;
  }
#pragma unroll
  for (int off = 32; off; off >>= 1)
#pragma unroll
    for (int c = 0; c < WAY; ++c) m[c] = fmaxf(m[c], __shfl_down(m[c], off));
  int wave = tid >> 6, lane = tid & 63;
  if (lane == 0)
    for (int c = 0; c < WAY; ++c) redm[c][wave] = m[c];
  __syncthreads();
  float M[WAY];
#pragma unroll
  for (int c = 0; c < WAY; ++c)
    M[c] = fmaxf(fmaxf(redm[c][0], redm[c][1]), fmaxf(redm[c][2], redm[c][3]));
  float s[WAY] = {};
#pragma unroll
  for (int it = 0; it < 6; ++it) {
    if (lc[it] >= 0) {
      v[it] = expf(v[it] - M[lc[it]]);
      s[lc[it]] += v[it];
    }
  }
#pragma unroll
  for (int off = 32; off; off >>= 1)
#pragma unroll
    for (int c = 0; c < WAY; ++c) s[c] += __shfl_down(s[c], off);
  if (lane == 0)
    for (int c = 0; c < WAY; ++c) reds[c][wave] = s[c];
  __syncthreads();
  float S[WAY];
#pragma unroll
  for (int c = 0; c < WAY; ++c) S[c] = reds[c][0] + reds[c][1] + reds[c][2] + reds[c][3];
#pragma unroll
  for (int it = 0; it < 6; ++it) {
    int col = it * 256 + tid;
    if (lc[it] >= 0) p[col] = v[it] / S[lc[it]];
  }
}

// ---------------- kernel 6: proto GEMM + fused distance ----------------
__global__ __launch_bounds__(256) void k_proto_dist(const float* __restrict__ AT,
                                                    const float* __restrict__ SVm,
                                                    const float* __restrict__ QVm,
                                                    const int* __restrict__ labels,
                                                    float* __restrict__ dist) {
  __shared__ float As[8][128];
  __shared__ float Bs[8][128];
  __shared__ int cs[NSUP];
  __shared__ int cntS;
  __shared__ float rowsum[128];
  int bn = blockIdx.x, bm = blockIdx.y, c = blockIdx.z;
  int tid = threadIdx.x;
  if (tid == 0) {
    int cnt = 0;
    for (int ss = 0; ss < NSUP; ++ss)
      if (labels[ss] == c) cs[cnt++] = ss;
    cntS = cnt;
  }
  __syncthreads();
  int K = cntS * NTUP;  // 280 for 5-shot; always multiple of 8
  int row0 = bm * 128, d0 = bn * 128;
  int lr = tid >> 1, lk = (tid & 1) * 4;
  int arow = min(row0 + lr, QROWS - 1);
  int bkr = tid >> 5, bd = (tid & 31) * 4;
  int tx = tid & 15, ty = tid >> 4;
  float acc[8][8] = {};
  for (int k0 = 0; k0 < K; k0 += 8) {
    float a4[4];
#pragma unroll
    for (int i = 0; i < 4; ++i) {
      int key = k0 + lk + i;
      int clip = cs[key / NTUP];
      int kt = key % NTUP;
      a4[i] = AT[(size_t)arow * SC_STRIDE + clip * NTUP + kt];
    }
    int keyb = k0 + bkr;
    int clipb = cs[keyb / NTUP];
    int ktb = keyb % NTUP;
    float4 b4 = *(const float4*)(SVm + (size_t)(clipb * NTUP + ktb) * OUT_DIM + d0 + bd);
    As[lk + 0][lr] = a4[0]; As[lk + 1][lr] = a4[1]; As[lk + 2][lr] = a4[2]; As[lk + 3][lr] = a4[3];
    *(float4*)&Bs[bkr][bd] = b4;
    __syncthreads();
#pragma unroll
    for (int kk = 0; kk < 8; ++kk) {
      float a8[8], b8[8];
      *(float4*)&a8[0] = *(const float4*)&As[kk][ty * 8];
      *(float4*)&a8[4] = *(const float4*)&As[kk][ty * 8 + 4];
      *(float4*)&b8[0] = *(const float4*)&Bs[kk][tx * 8];
      *(float4*)&b8[4] = *(const float4*)&Bs[kk][tx * 8 + 4];
#pragma unroll
      for (int i = 0; i < 8; ++i)
#pragma unroll
        for (int jj = 0; jj < 8; ++jj) acc[i][jj] += a8[i] * b8[jj];
    }
    __syncthreads();
  }
  // epilogue: sum (qv - proto)^2 per row
  float part[8];
#pragma unroll
  for (int i = 0; i < 8; ++i) {
    part[i] = 0.f;
    int row = row0 + ty * 8 + i;
    if (row < QROWS) {
      const float* qv = QVm + (size_t)row * OUT_DIM + d0 + tx * 8;
      float sacc = 0.f;
#pragma unroll
      for (int jj = 0; jj < 8; ++jj) {
        float dfe = qv[jj] - acc[i][jj];
        sacc += dfe * dfe;
      }
      part[i] = sacc;
    }
  }
  if (tid < 128) rowsum[tid] = 0.f;
  __syncthreads();
#pragma unroll
  for (int i = 0; i < 8; ++i) atomicAdd(&rowsum[ty * 8 + i], part[i]);
  __syncthreads();
  if (tid < 128) {
    int row = row0 + tid;
    if (row < QROWS) atomicAdd(&dist[c * NQ + row / NTUP], rowsum[tid]);
  }
}

// ---------------- kernel 7: finalize logits ----------------
__global__ void k_final(const float* __restrict__ dist, float* __restrict__ out) {
  int idx = blockIdx.x * blockDim.x + threadIdx.x;
  if (idx < NQ * WAY) {
    int q = idx / WAY, c = idx % WAY;
    out[idx] = -dist[c * NQ + q] * (1.f / NTUP);
  }
}

// ---------------- launch ----------------
extern "C" void kernel_launch(void* const* d_in, const int* in_sizes, int n_in,
                              void* d_out, int out_size, void* d_ws, size_t ws_size,
                              hipStream_t stream) {
  const float* support = (const float*)d_in[0];
  const int* labels = (const int*)d_in[1];
  const float* queries = (const float*)d_in[2];
  const float* Wk = (const float*)d_in[3];
  const float* bk = (const float*)d_in[4];
  const float* Wv = (const float*)d_in[5];
  const float* bv = (const float*)d_in[6];
  const float* ln_g = (const float*)d_in[7];
  const float* ln_b = (const float*)d_in[8];
  float* out = (float*)d_out;
  float* ws = (float*)d_ws;

  float* PE = ws + PE_OFF;
  float* AP = ws + AP_OFF;
  float* P = ws + P_OFF;
  float* QK = ws + QK_OFF;
  float* SK = ws + SK_OFF;
  float* QV = ws + QV_OFF;
  float* SV = ws + SV_OFF;
  float* SC = ws + SC_OFF;
  float* DIST = ws + DIST_OFF;

  k_pe_init<<<dim3(9), dim3(256), 0, stream>>>(PE, DIST);
  k_add_pe<<<dim3(3600), dim3(256), 0, stream>>>(support, queries, PE, AP);
  k_gemm1<<<dim3(54, 15), dim3(256), 0, stream>>>(AP, Wk, Wv, P);
  k_combine<<<dim3(12600, 2), dim3(192), 0, stream>>>(P, bk, bv, ln_g, ln_b, SK, QK, SV, QV);
  k_scores<<<dim3(11, 88), dim3(256), 0, stream>>>(QK, SK, SC);
  k_softmax<<<dim3(11200), dim3(256), 0, stream>>>(SC, labels);
  k_proto_dist<<<dim3(9, 88, 5), dim3(256), 0, stream>>>(SC, SV, QV, labels, DIST);
  k_final<<<dim3(4), dim3(256), 0, stream>>>(DIST, out);
}

// Round 2
// 1020.217 us; speedup vs baseline: 2.4331x; 2.4331x over previous
//
#include <hip/hip_runtime.h>
#include <math.h>

// ---------------- problem constants ----------------
#define SEQ_LEN 8
#define IN_DIM 2048
#define OUT_DIM 1152
#define NTUP 56
#define NSUP 25
#define NQ 200
#define WAY 5
#define SFRAMES 200
#define NFRAMES 1800
#define SROWS 1400
#define QROWS 11200
#define SC_STRIDE 1408   // fp32 scores row stride
#define AT_STRIDE 1440   // bf16 attn row stride: 5 classes * 288
#define KC 288           // per-class padded K (280 valid + 8 zeros)

typedef __attribute__((ext_vector_type(8))) short short8;
typedef __attribute__((ext_vector_type(4))) float f32x4;

__device__ __constant__ int TUP[NTUP][3] = {
{0,1,2},{0,1,3},{0,1,4},{0,1,5},{0,1,6},{0,1,7},
{0,2,3},{0,2,4},{0,2,5},{0,2,6},{0,2,7},
{0,3,4},{0,3,5},{0,3,6},{0,3,7},
{0,4,5},{0,4,6},{0,4,7},
{0,5,6},{0,5,7},
{0,6,7},
{1,2,3},{1,2,4},{1,2,5},{1,2,6},{1,2,7},
{1,3,4},{1,3,5},{1,3,6},{1,3,7},
{1,4,5},{1,4,6},{1,4,7},
{1,5,6},{1,5,7},
{1,6,7},
{2,3,4},{2,3,5},{2,3,6},{2,3,7},
{2,4,5},{2,4,6},{2,4,7},
{2,5,6},{2,5,7},
{2,6,7},
{3,4,5},{3,4,6},{3,4,7},
{3,5,6},{3,5,7},
{3,6,7},
{4,5,6},{4,5,7},
{4,6,7},
{5,6,7}};

// ---------------- bf16 helpers ----------------
__device__ __forceinline__ unsigned short f2bf(float x) {
  union { float f; unsigned int u; } v; v.f = x;
  unsigned int r = v.u + 0x7fffu + ((v.u >> 16) & 1u);
  return (unsigned short)(r >> 16);
}
__device__ __forceinline__ float bf2f(unsigned short s) {
  union { float f; unsigned int u; } v; v.u = ((unsigned int)s) << 16;
  return v.f;
}

// async 16B global -> LDS (lane-indexed dest = wave-uniform base + lane*16)
__device__ __forceinline__ void gll16(const void* g, void* l) {
  __builtin_amdgcn_global_load_lds(
      (const __attribute__((address_space(1))) unsigned int*)g,
      (__attribute__((address_space(3))) unsigned int*)l, 16, 0, 0);
}

// ---------------- workspace byte offsets ----------------
#define PE_OFF    0UL                     // f32 [8][2048]            65536
#define APB_OFF   65536UL                 // bf16 [1800][2048]        7372800
#define WT_OFF    7438336UL               // bf16 [6912][2048]        28311552
#define PB_OFF    35749888UL              // bf16 [1800][6912]        24883200
#define QKB_OFF   60633088UL              // bf16 [11200][1152]       25804800
#define SKB_OFF   86437888UL              // bf16 [1400][1152]        3225600+pad
#define QV_OFF    89681920UL              // f32  [11200][1152]       51609600
#define SVB_OFF   141291520UL             // bf16 [1400][1152] sorted 3225600
#define SVT_OFF   144517120UL             // bf16 [5][1152][288]      3317760
#define SC_OFF    147834880UL             // f32  [11200][1408]       63078400
#define ATB_OFF   210913280UL             // bf16 [11200][1440]       32256000
#define DIST_OFF  243169280UL             // f32  [5][200]            4096
#define RANK_OFF  243173376UL             // i32  [25]

// ---------------- kernel: PE table + dist zero + class rank ----------------
__global__ void k_init(float* __restrict__ pe, float* __restrict__ dist,
                       const int* __restrict__ labels, int* __restrict__ rank) {
  int b = blockIdx.x, tid = threadIdx.x;
  if (b < SEQ_LEN) {
    const float c0 = -logf(10000.0f) / (float)IN_DIM;
    for (int i = tid; i < IN_DIM / 2; i += blockDim.x) {
      float dt = expf((float)(2 * i) * c0);
      float arg = (float)b * dt;
      pe[b * IN_DIM + 2 * i]     = sinf(arg) * 0.1f;
      pe[b * IN_DIM + 2 * i + 1] = cosf(arg) * 0.1f;
    }
  } else {
    for (int i = tid; i < WAY * NQ; i += blockDim.x) dist[i] = 0.f;
    if (tid == 0) {
      for (int s = 0; s < NSUP; ++s) {
        int r = 0;
        for (int s2 = 0; s2 < NSUP; ++s2)
          r += (labels[s2] < labels[s]) || (labels[s2] == labels[s] && s2 < s);
        rank[s] = r;
      }
    }
  }
}

// ---------------- kernel: A' = bf16(X + PE) ----------------
__global__ __launch_bounds__(256) void k_add_pe(const float* __restrict__ S,
                                                const float* __restrict__ Q,
                                                const float* __restrict__ pe,
                                                unsigned short* __restrict__ APb) {
  int idx = blockIdx.x * 256 + threadIdx.x;   // 460800 = 1800 * 256
  int frame = idx >> 8;
  int e8 = (idx & 255) * 8;
  int pos = frame & 7;
  const float* src = (frame < SFRAMES) ? (S + (size_t)frame * IN_DIM + e8)
                                       : (Q + (size_t)(frame - SFRAMES) * IN_DIM + e8);
  const float* pp = pe + (size_t)pos * IN_DIM + e8;
  float4 x0 = ((const float4*)src)[0], x1 = ((const float4*)src)[1];
  float4 p0 = ((const float4*)pp)[0], p1 = ((const float4*)pp)[1];
  short8 o;
  o[0] = (short)f2bf(x0.x + p0.x); o[1] = (short)f2bf(x0.y + p0.y);
  o[2] = (short)f2bf(x0.z + p0.z); o[3] = (short)f2bf(x0.w + p0.w);
  o[4] = (short)f2bf(x1.x + p1.x); o[5] = (short)f2bf(x1.y + p1.y);
  o[6] = (short)f2bf(x1.z + p1.z); o[7] = (short)f2bf(x1.w + p1.w);
  *(short8*)(APb + (size_t)frame * IN_DIM + e8) = o;
}

// ---------------- kernel: weight transpose+convert  WT[col][k] ----------------
__global__ __launch_bounds__(256) void k_wt(const float* __restrict__ Wk,
                                            const float* __restrict__ Wv,
                                            unsigned short* __restrict__ WT) {
  __shared__ float t[32][33];
  int z = blockIdx.z; int w = z / 3, j = z % 3;
  const float* W = w ? Wv : Wk;
  int k0 = blockIdx.x * 32, d0 = blockIdx.y * 32;
  int tx = threadIdx.x, ty = threadIdx.y;
#pragma unroll
  for (int i = 0; i < 4; ++i) {
    int k = k0 + ty + i * 8;
    t[ty + i * 8][tx] = W[(size_t)(j * IN_DIM + k) * OUT_DIM + d0 + tx];
  }
  __syncthreads();
  int colbase = w * 3456 + j * 1152 + d0;
#pragma unroll
  for (int i = 0; i < 4; ++i) {
    int d = ty + i * 8;
    WT[(size_t)(colbase + d) * IN_DIM + k0 + tx] = f2bf(t[tx][d]);
  }
}

// ---------------- MFMA GEMM core (m97 structure) ----------------
// Both operands bf16 in [rows][K] layout (k-contiguous). 128x128 tile, BK=32.
// acc layout per 16x16 tile: D[row=quad*4+r][col=lane&15].
__device__ __forceinline__ void mfma_core(const short* __restrict__ A, int lda, int maxA,
                                          const short* __restrict__ B, int ldb, int maxB,
                                          int K, short* lds, f32x4 (&acc)[4][4]) {
  int tid = threadIdx.x;
  int lane = tid & 63, wave = tid >> 6;
  int wm = wave & 1, wn = wave >> 1;
  int col = lane & 15, quad = lane >> 4;
  short* As = lds;           // [128][32]
  short* Bs = lds + 4096;    // [128][32]
  int s0 = tid, s1 = tid + 256;
  int r0 = s0 >> 2, r1 = s1 >> 2;
  int o0 = (s0 & 3) * 8, o1 = (s1 & 3) * 8;
  const short* a0p = A + (size_t)min(r0, maxA) * lda + o0;
  const short* a1p = A + (size_t)min(r1, maxA) * lda + o1;
  const short* b0p = B + (size_t)min(r0, maxB) * ldb + o0;
  const short* b1p = B + (size_t)min(r1, maxB) * ldb + o1;
  short* la0 = As + s0 * 8; short* la1 = As + s1 * 8;
  short* lb0 = Bs + s0 * 8; short* lb1 = Bs + s1 * 8;

  for (int k0 = 0; k0 < K; k0 += 32) {
    gll16(a0p + k0, la0);
    gll16(a1p + k0, la1);
    gll16(b0p + k0, lb0);
    gll16(b1p + k0, lb1);
    __syncthreads();
    short8 af[4], bf[4];
#pragma unroll
    for (int i = 0; i < 4; ++i)
      af[i] = *(const short8*)(As + (wm * 64 + i * 16 + col) * 32 + quad * 8);
#pragma unroll
    for (int j = 0; j < 4; ++j)
      bf[j] = *(const short8*)(Bs + (wn * 64 + j * 16 + col) * 32 + quad * 8);
#pragma unroll
    for (int i = 0; i < 4; ++i)
#pragma unroll
      for (int j = 0; j < 4; ++j)
        acc[i][j] = __builtin_amdgcn_mfma_f32_16x16x32_bf16(af[i], bf[j], acc[i][j], 0, 0, 0);
    __syncthreads();
  }
}

// ---------------- GEMM1: Pb[1800][6912] = APb @ WT^T (both k-major) ----------------
__global__ __launch_bounds__(256) void k_gemm1(const unsigned short* __restrict__ APb,
                                               const unsigned short* __restrict__ WT,
                                               unsigned short* __restrict__ Pb) {
  __shared__ short lds[8192];
  int row0 = blockIdx.y * 128, col0 = blockIdx.x * 128;
  f32x4 acc[4][4];
#pragma unroll
  for (int i = 0; i < 4; ++i)
#pragma unroll
    for (int j = 0; j < 4; ++j) acc[i][j] = (f32x4)(0.f);
  mfma_core((const short*)APb + (size_t)row0 * IN_DIM, IN_DIM, min(127, NFRAMES - 1 - row0),
            (const short*)WT + (size_t)col0 * IN_DIM, IN_DIM, 127,
            IN_DIM, lds, acc);
  int lane = threadIdx.x & 63, wave = threadIdx.x >> 6;
  int wm = wave & 1, wn = wave >> 1, col = lane & 15, quad = lane >> 4;
#pragma unroll
  for (int i = 0; i < 4; ++i)
#pragma unroll
    for (int r = 0; r < 4; ++r) {
      int gr = row0 + wm * 64 + i * 16 + quad * 4 + r;
      if (gr >= NFRAMES) continue;
#pragma unroll
      for (int j = 0; j < 4; ++j)
        Pb[(size_t)gr * 6912 + col0 + wn * 64 + j * 16 + col] = f2bf(acc[i][j][r]);
    }
}

// ---------------- combine: sum 3 frame projections, +bias, LN(k), sorted support ----------------
__global__ __launch_bounds__(192) void k_combine(const unsigned short* __restrict__ Pb,
                                                 const float* __restrict__ bk,
                                                 const float* __restrict__ bv,
                                                 const float* __restrict__ g,
                                                 const float* __restrict__ bb,
                                                 const int* __restrict__ rank,
                                                 unsigned short* __restrict__ SKb,
                                                 unsigned short* __restrict__ QKb,
                                                 unsigned short* __restrict__ SVb,
                                                 float* __restrict__ QV) {
  int row = blockIdx.x;     // 0..12599
  int w = blockIdx.y;       // 0 = k, 1 = v
  int tid = threadIdx.x;
  bool isq = row >= SROWS;
  int r = isq ? row - SROWS : row;
  int n = r / NTUP, t = r - n * NTUP;
  int orow = isq ? r : (rank[n] * NTUP + t);  // class-sorted support rows
  int fbase = (isq ? SFRAMES + n * SEQ_LEN : n * SEQ_LEN);
  const unsigned short* p0 = Pb + (size_t)(fbase + TUP[t][0]) * 6912 + w * 3456;
  const unsigned short* p1 = Pb + (size_t)(fbase + TUP[t][1]) * 6912 + w * 3456 + 1152;
  const unsigned short* p2 = Pb + (size_t)(fbase + TUP[t][2]) * 6912 + w * 3456 + 2304;
  const float* bias = w ? bv : bk;
  float v[6];
  float sum = 0.f, sq = 0.f;
#pragma unroll
  for (int i = 0; i < 6; ++i) {
    int d = tid + i * 192;
    v[i] = bf2f(p0[d]) + bf2f(p1[d]) + bf2f(p2[d]) + bias[d];
    sum += v[i];
    sq += v[i] * v[i];
  }
  if (w == 0) {
#pragma unroll
    for (int off = 32; off; off >>= 1) {
      sum += __shfl_down(sum, off);
      sq += __shfl_down(sq, off);
    }
    __shared__ float s1[3], s2[3];
    int wavei = tid >> 6, lane = tid & 63;
    if (lane == 0) { s1[wavei] = sum; s2[wavei] = sq; }
    __syncthreads();
    float tot = s1[0] + s1[1] + s1[2];
    float tot2 = s2[0] + s2[1] + s2[2];
    float mean = tot * (1.f / OUT_DIM);
    float var = tot2 * (1.f / OUT_DIM) - mean * mean;
    float inv = rsqrtf(var + 1e-5f);
    unsigned short* outp = isq ? (QKb + (size_t)orow * OUT_DIM) : (SKb + (size_t)orow * OUT_DIM);
#pragma unroll
    for (int i = 0; i < 6; ++i) {
      int d = tid + i * 192;
      outp[d] = f2bf((v[i] - mean) * inv * g[d] + bb[d]);
    }
  } else {
    if (isq) {
      float* outp = QV + (size_t)orow * OUT_DIM;
#pragma unroll
      for (int i = 0; i < 6; ++i) outp[tid + i * 192] = v[i];
    } else {
      unsigned short* outp = SVb + (size_t)orow * OUT_DIM;
#pragma unroll
      for (int i = 0; i < 6; ++i) outp[tid + i * 192] = f2bf(v[i]);
    }
  }
}

// ---------------- SV transpose: SVT[c][d][kk] (zero-padded to 288) ----------------
__global__ __launch_bounds__(256) void k_svt(const unsigned short* __restrict__ SVb,
                                             unsigned short* __restrict__ SVT) {
  __shared__ unsigned short t[32][33];
  int c = blockIdx.z;
  int k0 = blockIdx.x * 32, d0 = blockIdx.y * 32;
  int tx = threadIdx.x, ty = threadIdx.y;
#pragma unroll
  for (int i = 0; i < 4; ++i) {
    int k = k0 + ty + i * 8;
    t[ty + i * 8][tx] = (k < 280) ? SVb[(size_t)(c * 280 + k) * OUT_DIM + d0 + tx] : 0;
  }
  __syncthreads();
#pragma unroll
  for (int i = 0; i < 4; ++i) {
    int d = d0 + ty + i * 8;
    SVT[((size_t)c * OUT_DIM + d) * KC + k0 + tx] = t[tx][ty + i * 8];
  }
}

// ---------------- scores: SC[11200][1408] = (QKb @ SKb^T) * scale ----------------
__global__ __launch_bounds__(256) void k_scores(const unsigned short* __restrict__ QKb,
                                                const unsigned short* __restrict__ SKb,
                                                float* __restrict__ SC) {
  __shared__ short lds[8192];
  int row0 = blockIdx.y * 128, col0 = blockIdx.x * 128;
  f32x4 acc[4][4];
#pragma unroll
  for (int i = 0; i < 4; ++i)
#pragma unroll
    for (int j = 0; j < 4; ++j) acc[i][j] = (f32x4)(0.f);
  mfma_core((const short*)QKb + (size_t)row0 * OUT_DIM, OUT_DIM, min(127, QROWS - 1 - row0),
            (const short*)SKb + (size_t)col0 * OUT_DIM, OUT_DIM, min(127, SROWS - 1 - col0),
            OUT_DIM, lds, acc);
  const float scale = 0.029462782549439483f;  // 1/sqrt(1152)
  int lane = threadIdx.x & 63, wave = threadIdx.x >> 6;
  int wm = wave & 1, wn = wave >> 1, col = lane & 15, quad = lane >> 4;
#pragma unroll
  for (int i = 0; i < 4; ++i)
#pragma unroll
    for (int r = 0; r < 4; ++r) {
      int gr = row0 + wm * 64 + i * 16 + quad * 4 + r;
      if (gr >= QROWS) continue;
#pragma unroll
      for (int j = 0; j < 4; ++j) {
        int gc = col0 + wn * 64 + j * 16 + col;
        if (gc < SROWS) SC[(size_t)gr * SC_STRIDE + gc] = acc[i][j][r] * scale;
      }
    }
}

// ---------------- per-class softmax (class-sorted cols) -> bf16 attn ----------------
__global__ __launch_bounds__(256) void k_softmax(const float* __restrict__ SC,
                                                 unsigned short* __restrict__ ATb) {
  int row = blockIdx.x, tid = threadIdx.x;
  const float* p = SC + (size_t)row * SC_STRIDE;
  __shared__ float redm[WAY][4];
  __shared__ float reds[WAY][4];
  float v[6];
  int cls[6], loc[6];
  float m[WAY];
#pragma unroll
  for (int c = 0; c < WAY; ++c) m[c] = -INFINITY;
#pragma unroll
  for (int it = 0; it < 6; ++it) {
    int colx = it * 256 + tid;
    if (colx < SROWS) {
      v[it] = p[colx];
      int c = colx / 280;
      cls[it] = c; loc[it] = colx - c * 280;
      m[c] = fmaxf(m[c], v[it]);
    } else cls[it] = -1;
  }
#pragma unroll
  for (int off = 32; off; off >>= 1)
#pragma unroll
    for (int c = 0; c < WAY; ++c) m[c] = fmaxf(m[c], __shfl_xor(m[c], off));
  int wavei = tid >> 6, lane = tid & 63;
  if (lane == 0)
#pragma unroll
    for (int c = 0; c < WAY; ++c) redm[c][wavei] = m[c];
  __syncthreads();
  float M[WAY];
#pragma unroll
  for (int c = 0; c < WAY; ++c)
    M[c] = fmaxf(fmaxf(redm[c][0], redm[c][1]), fmaxf(redm[c][2], redm[c][3]));
  float s[WAY];
#pragma unroll
  for (int c = 0; c < WAY; ++c) s[c] = 0.f;
#pragma unroll
  for (int it = 0; it < 6; ++it)
    if (cls[it] >= 0) {
      v[it] = expf(v[it] - M[cls[it]]);
      s[cls[it]] += v[it];
    }
#pragma unroll
  for (int off = 32; off; off >>= 1)
#pragma unroll
    for (int c = 0; c < WAY; ++c) s[c] += __shfl_xor(s[c], off);
  if (lane == 0)
#pragma unroll
    for (int c = 0; c < WAY; ++c) reds[c][wavei] = s[c];
  __syncthreads();
  float S[WAY];
#pragma unroll
  for (int c = 0; c < WAY; ++c) S[c] = reds[c][0] + reds[c][1] + reds[c][2] + reds[c][3];
  unsigned short* op = ATb + (size_t)row * AT_STRIDE;
#pragma unroll
  for (int it = 0; it < 6; ++it)
    if (cls[it] >= 0) op[cls[it] * KC + loc[it]] = f2bf(v[it] / S[cls[it]]);
  if (tid < WAY * 8) op[(tid >> 3) * KC + 280 + (tid & 7)] = 0;  // zero pads
}

// ---------------- proto GEMM + fused distance ----------------
__global__ __launch_bounds__(256) void k_proto(const unsigned short* __restrict__ ATb,
                                               const unsigned short* __restrict__ SVT,
                                               const float* __restrict__ QV,
                                               float* __restrict__ dist) {
  __shared__ short lds[8192];
  __shared__ float rowsum[128];
  int c = blockIdx.z;
  int row0 = blockIdx.y * 128, d0 = blockIdx.x * 128;
  int tid = threadIdx.x;
  if (tid < 128) rowsum[tid] = 0.f;
  f32x4 acc[4][4];
#pragma unroll
  for (int i = 0; i < 4; ++i)
#pragma unroll
    for (int j = 0; j < 4; ++j) acc[i][j] = (f32x4)(0.f);
  mfma_core((const short*)ATb + (size_t)row0 * AT_STRIDE + c * KC, AT_STRIDE,
            min(127, QROWS - 1 - row0),
            (const short*)SVT + ((size_t)c * OUT_DIM + d0) * KC, KC, 127,
            KC, lds, acc);
  int lane = tid & 63, wave = tid >> 6;
  int wm = wave & 1, wn = wave >> 1, col = lane & 15, quad = lane >> 4;
#pragma unroll
  for (int i = 0; i < 4; ++i)
#pragma unroll
    for (int r = 0; r < 4; ++r) {
      int rl = wm * 64 + i * 16 + quad * 4 + r;
      int gr = row0 + rl;
      float sacc = 0.f;
      if (gr < QROWS) {
        const float* qv = QV + (size_t)gr * OUT_DIM + d0 + wn * 64 + col;
#pragma unroll
        for (int j = 0; j < 4; ++j) {
          float d = qv[j * 16] - acc[i][j][r];
          sacc += d * d;
        }
      }
#pragma unroll
      for (int mm = 1; mm < 16; mm <<= 1) sacc += __shfl_xor(sacc, mm);
      if (col == 0) atomicAdd(&rowsum[rl], sacc);
    }
  __syncthreads();
  if (tid < 128) {
    int gr = row0 + tid;
    if (gr < QROWS) atomicAdd(&dist[c * NQ + gr / NTUP], rowsum[tid]);
  }
}

// ---------------- finalize ----------------
__global__ void k_final(const float* __restrict__ dist, float* __restrict__ out) {
  int idx = blockIdx.x * blockDim.x + threadIdx.x;
  if (idx < NQ * WAY) {
    int q = idx / WAY, c = idx % WAY;
    out[idx] = -dist[c * NQ + q] * (1.f / NTUP);
  }
}

// ---------------- launch ----------------
extern "C" void kernel_launch(void* const* d_in, const int* in_sizes, int n_in,
                              void* d_out, int out_size, void* d_ws, size_t ws_size,
                              hipStream_t stream) {
  const float* support = (const float*)d_in[0];
  const int* labels = (const int*)d_in[1];
  const float* queries = (const float*)d_in[2];
  const float* Wk = (const float*)d_in[3];
  const float* bk = (const float*)d_in[4];
  const float* Wv = (const float*)d_in[5];
  const float* bv = (const float*)d_in[6];
  const float* ln_g = (const float*)d_in[7];
  const float* ln_b = (const float*)d_in[8];
  float* out = (float*)d_out;
  char* w8 = (char*)d_ws;

  float* PE = (float*)(w8 + PE_OFF);
  unsigned short* APb = (unsigned short*)(w8 + APB_OFF);
  unsigned short* WT = (unsigned short*)(w8 + WT_OFF);
  unsigned short* Pb = (unsigned short*)(w8 + PB_OFF);
  unsigned short* QKb = (unsigned short*)(w8 + QKB_OFF);
  unsigned short* SKb = (unsigned short*)(w8 + SKB_OFF);
  float* QV = (float*)(w8 + QV_OFF);
  unsigned short* SVb = (unsigned short*)(w8 + SVB_OFF);
  unsigned short* SVT = (unsigned short*)(w8 + SVT_OFF);
  float* SC = (float*)(w8 + SC_OFF);
  unsigned short* ATb = (unsigned short*)(w8 + ATB_OFF);
  float* DIST = (float*)(w8 + DIST_OFF);
  int* RANK = (int*)(w8 + RANK_OFF);

  k_init<<<dim3(9), dim3(256), 0, stream>>>(PE, DIST, labels, RANK);
  k_add_pe<<<dim3(1800), dim3(256), 0, stream>>>(support, queries, PE, APb);
  k_wt<<<dim3(64, 36, 6), dim3(32, 8), 0, stream>>>(Wk, Wv, WT);
  k_gemm1<<<dim3(54, 15), dim3(256), 0, stream>>>(APb, WT, Pb);
  k_combine<<<dim3(12600, 2), dim3(192), 0, stream>>>(Pb, bk, bv, ln_g, ln_b, RANK,
                                                      SKb, QKb, SVb, QV);
  k_svt<<<dim3(9, 36, 5), dim3(32, 8), 0, stream>>>(SVb, SVT);
  k_scores<<<dim3(11, 88), dim3(256), 0, stream>>>(QKb, SKb, SC);
  k_softmax<<<dim3(11200), dim3(256), 0, stream>>>(SC, ATb);
  k_proto<<<dim3(9, 88, 5), dim3(256), 0, stream>>>(ATb, SVT, QV, DIST);
  k_final<<<dim3(4), dim3(256), 0, stream>>>(DIST, out);
}

// Round 3
// 522.986 us; speedup vs baseline: 4.7464x; 1.9508x over previous
//
#include <hip/hip_runtime.h>
#include <math.h>

// ---------------- problem constants ----------------
#define SEQ_LEN 8
#define IN_DIM 2048
#define OUT_DIM 1152
#define NTUP 56
#define NSUP 25
#define NQ 200
#define WAY 5
#define SFRAMES 200
#define NFRAMES 1800
#define SROWS 1400
#define QROWS 11200
#define SC_STRIDE 1408   // fp32 scores row stride
#define AT_STRIDE 1440   // bf16 attn/G1 row stride: 5 classes * 288
#define KC 288           // per-class padded K (280 valid + 8 zeros)

typedef __attribute__((ext_vector_type(8))) short short8;
typedef __attribute__((ext_vector_type(4))) float f32x4;

__device__ __constant__ int TUP[NTUP][3] = {
{0,1,2},{0,1,3},{0,1,4},{0,1,5},{0,1,6},{0,1,7},
{0,2,3},{0,2,4},{0,2,5},{0,2,6},{0,2,7},
{0,3,4},{0,3,5},{0,3,6},{0,3,7},
{0,4,5},{0,4,6},{0,4,7},
{0,5,6},{0,5,7},
{0,6,7},
{1,2,3},{1,2,4},{1,2,5},{1,2,6},{1,2,7},
{1,3,4},{1,3,5},{1,3,6},{1,3,7},
{1,4,5},{1,4,6},{1,4,7},
{1,5,6},{1,5,7},
{1,6,7},
{2,3,4},{2,3,5},{2,3,6},{2,3,7},
{2,4,5},{2,4,6},{2,4,7},
{2,5,6},{2,5,7},
{2,6,7},
{3,4,5},{3,4,6},{3,4,7},
{3,5,6},{3,5,7},
{3,6,7},
{4,5,6},{4,5,7},
{4,6,7},
{5,6,7}};

// ---------------- bf16 helpers ----------------
__device__ __forceinline__ unsigned short f2bf(float x) {
  union { float f; unsigned int u; } v; v.f = x;
  unsigned int r = v.u + 0x7fffu + ((v.u >> 16) & 1u);
  return (unsigned short)(r >> 16);
}
__device__ __forceinline__ float bf2f(unsigned short s) {
  union { float f; unsigned int u; } v; v.u = ((unsigned int)s) << 16;
  return v.f;
}

// async 16B global -> LDS
__device__ __forceinline__ void gll16(const void* g, void* l) {
  __builtin_amdgcn_global_load_lds(
      (const __attribute__((address_space(1))) unsigned int*)g,
      (__attribute__((address_space(3))) unsigned int*)l, 16, 0, 0);
}

// ---------------- workspace byte offsets ----------------
#define PE_OFF    0UL                     // f32 [8][2048]
#define APB_OFF   65536UL                 // bf16 [1800][2048]
#define WT_OFF    7438336UL               // bf16 [6912][2048]
#define PB_OFF    35749888UL              // bf16 [1800][6912]
#define QKB_OFF   60633088UL              // bf16 [11200][1152]
#define SKB_OFF   86437888UL              // bf16 [1400][1152] class-sorted
#define QVB_OFF   89663488UL              // bf16 [11200][1152]
#define SVB_OFF   115468288UL             // bf16 [1400][1152] class-sorted
#define SVT_OFF   118693888UL             // bf16 [5][1152][288]
#define SC_OFF    122011648UL             // f32  [11200][1408]
#define G1B_OFF   185090048UL             // bf16 [11200][1440] class-padded
#define ATB_OFF   217346048UL             // bf16 [11200][1440] class-padded
#define QNORM_OFF 249602048UL             // f32  [11200]
#define T2_OFF    249646848UL             // f32  [5][11200]
#define T3_OFF    249870848UL             // f32  [5][11200]
#define RANK_OFF  250094848UL             // i32  [25]

// ---------------- init: PE table + rank + zero TERM3 ----------------
__global__ void k_init(float* __restrict__ pe, const int* __restrict__ labels,
                       int* __restrict__ rank, float* __restrict__ t3) {
  int b = blockIdx.x, tid = threadIdx.x;
  if (b < SEQ_LEN) {
    const float c0 = -logf(10000.0f) / (float)IN_DIM;
    for (int i = tid; i < IN_DIM / 2; i += blockDim.x) {
      float dt = expf((float)(2 * i) * c0);
      float arg = (float)b * dt;
      pe[b * IN_DIM + 2 * i]     = sinf(arg) * 0.1f;
      pe[b * IN_DIM + 2 * i + 1] = cosf(arg) * 0.1f;
    }
  } else {
    int idx = (b - 8) * 256 + tid;
    if (idx < WAY * QROWS) t3[idx] = 0.f;
    if (b == 8 && tid == 0) {
      for (int s = 0; s < NSUP; ++s) {
        int r = 0;
        for (int s2 = 0; s2 < NSUP; ++s2)
          r += (labels[s2] < labels[s]) || (labels[s2] == labels[s] && s2 < s);
        rank[s] = r;
      }
    }
  }
}

// ---------------- A' = bf16(X + PE) ----------------
__global__ __launch_bounds__(256) void k_add_pe(const float* __restrict__ S,
                                                const float* __restrict__ Q,
                                                const float* __restrict__ pe,
                                                unsigned short* __restrict__ APb) {
  int idx = blockIdx.x * 256 + threadIdx.x;
  int frame = idx >> 8;
  int e8 = (idx & 255) * 8;
  int pos = frame & 7;
  const float* src = (frame < SFRAMES) ? (S + (size_t)frame * IN_DIM + e8)
                                       : (Q + (size_t)(frame - SFRAMES) * IN_DIM + e8);
  const float* pp = pe + (size_t)pos * IN_DIM + e8;
  float4 x0 = ((const float4*)src)[0], x1 = ((const float4*)src)[1];
  float4 p0 = ((const float4*)pp)[0], p1 = ((const float4*)pp)[1];
  short8 o;
  o[0] = (short)f2bf(x0.x + p0.x); o[1] = (short)f2bf(x0.y + p0.y);
  o[2] = (short)f2bf(x0.z + p0.z); o[3] = (short)f2bf(x0.w + p0.w);
  o[4] = (short)f2bf(x1.x + p1.x); o[5] = (short)f2bf(x1.y + p1.y);
  o[6] = (short)f2bf(x1.z + p1.z); o[7] = (short)f2bf(x1.w + p1.w);
  *(short8*)(APb + (size_t)frame * IN_DIM + e8) = o;
}

// ---------------- weight transpose+convert  WT[col][k] ----------------
__global__ __launch_bounds__(256) void k_wt(const float* __restrict__ Wk,
                                            const float* __restrict__ Wv,
                                            unsigned short* __restrict__ WT) {
  __shared__ float t[32][33];
  int z = blockIdx.z; int w = z / 3, j = z % 3;
  const float* W = w ? Wv : Wk;
  int k0 = blockIdx.x * 32, d0 = blockIdx.y * 32;
  int tx = threadIdx.x, ty = threadIdx.y;
#pragma unroll
  for (int i = 0; i < 4; ++i) {
    int k = k0 + ty + i * 8;
    t[ty + i * 8][tx] = W[(size_t)(j * IN_DIM + k) * OUT_DIM + d0 + tx];
  }
  __syncthreads();
  int colbase = w * 3456 + j * 1152 + d0;
#pragma unroll
  for (int i = 0; i < 4; ++i) {
    int d = ty + i * 8;
    WT[(size_t)(colbase + d) * IN_DIM + k0 + tx] = f2bf(t[tx][d]);
  }
}

// ---------------- MFMA GEMM core (m97 structure) ----------------
__device__ __forceinline__ void mfma_core(const short* __restrict__ A, int lda, int maxA,
                                          const short* __restrict__ B, int ldb, int maxB,
                                          int K, short* lds, f32x4 (&acc)[4][4]) {
  int tid = threadIdx.x;
  int lane = tid & 63, wave = tid >> 6;
  int wm = wave & 1, wn = wave >> 1;
  int col = lane & 15, quad = lane >> 4;
  short* As = lds;           // [128][32]
  short* Bs = lds + 4096;    // [128][32]
  int s0 = tid, s1 = tid + 256;
  int r0 = s0 >> 2, r1 = s1 >> 2;
  int o0 = (s0 & 3) * 8, o1 = (s1 & 3) * 8;
  const short* a0p = A + (size_t)min(r0, maxA) * lda + o0;
  const short* a1p = A + (size_t)min(r1, maxA) * lda + o1;
  const short* b0p = B + (size_t)min(r0, maxB) * ldb + o0;
  const short* b1p = B + (size_t)min(r1, maxB) * ldb + o1;
  short* la0 = As + s0 * 8; short* la1 = As + s1 * 8;
  short* lb0 = Bs + s0 * 8; short* lb1 = Bs + s1 * 8;

  for (int k0 = 0; k0 < K; k0 += 32) {
    gll16(a0p + k0, la0);
    gll16(a1p + k0, la1);
    gll16(b0p + k0, lb0);
    gll16(b1p + k0, lb1);
    __syncthreads();
    short8 af[4], bf[4];
#pragma unroll
    for (int i = 0; i < 4; ++i)
      af[i] = *(const short8*)(As + (wm * 64 + i * 16 + col) * 32 + quad * 8);
#pragma unroll
    for (int j = 0; j < 4; ++j)
      bf[j] = *(const short8*)(Bs + (wn * 64 + j * 16 + col) * 32 + quad * 8);
#pragma unroll
    for (int i = 0; i < 4; ++i)
#pragma unroll
      for (int j = 0; j < 4; ++j)
        acc[i][j] = __builtin_amdgcn_mfma_f32_16x16x32_bf16(af[i], bf[j], acc[i][j], 0, 0, 0);
    __syncthreads();
  }
}

// ---------------- GEMM1: Pb[1800][6912] = APb @ WT^T ----------------
__global__ __launch_bounds__(256) void k_gemm1(const unsigned short* __restrict__ APb,
                                               const unsigned short* __restrict__ WT,
                                               unsigned short* __restrict__ Pb) {
  __shared__ short lds[8192];
  int row0 = blockIdx.y * 128, col0 = blockIdx.x * 128;
  f32x4 acc[4][4];
#pragma unroll
  for (int i = 0; i < 4; ++i)
#pragma unroll
    for (int j = 0; j < 4; ++j) acc[i][j] = (f32x4)(0.f);
  mfma_core((const short*)APb + (size_t)row0 * IN_DIM, IN_DIM, min(127, NFRAMES - 1 - row0),
            (const short*)WT + (size_t)col0 * IN_DIM, IN_DIM, 127,
            IN_DIM, lds, acc);
  int lane = threadIdx.x & 63, wave = threadIdx.x >> 6;
  int wm = wave & 1, wn = wave >> 1, col = lane & 15, quad = lane >> 4;
#pragma unroll
  for (int i = 0; i < 4; ++i)
#pragma unroll
    for (int r = 0; r < 4; ++r) {
      int gr = row0 + wm * 64 + i * 16 + quad * 4 + r;
      if (gr >= NFRAMES) continue;
#pragma unroll
      for (int j = 0; j < 4; ++j)
        Pb[(size_t)gr * 6912 + col0 + wn * 64 + j * 16 + col] = f2bf(acc[i][j][r]);
    }
}

// ---------------- combine: sum 3 frame projections, +bias, LN(k), qnorm(v) ----------------
__global__ __launch_bounds__(192) void k_combine(const unsigned short* __restrict__ Pb,
                                                 const float* __restrict__ bk,
                                                 const float* __restrict__ bv,
                                                 const float* __restrict__ g,
                                                 const float* __restrict__ bb,
                                                 const int* __restrict__ rank,
                                                 unsigned short* __restrict__ SKb,
                                                 unsigned short* __restrict__ QKb,
                                                 unsigned short* __restrict__ SVb,
                                                 unsigned short* __restrict__ QVb,
                                                 float* __restrict__ qnorm) {
  __shared__ float s1[3], s2[3];
  int row = blockIdx.x;     // 0..12599
  int w = blockIdx.y;       // 0 = k, 1 = v
  int tid = threadIdx.x;
  bool isq = row >= SROWS;
  int r = isq ? row - SROWS : row;
  int n = r / NTUP, t = r - n * NTUP;
  int orow = isq ? r : (rank[n] * NTUP + t);
  int fbase = (isq ? SFRAMES + n * SEQ_LEN : n * SEQ_LEN);
  const unsigned short* p0 = Pb + (size_t)(fbase + TUP[t][0]) * 6912 + w * 3456;
  const unsigned short* p1 = Pb + (size_t)(fbase + TUP[t][1]) * 6912 + w * 3456 + 1152;
  const unsigned short* p2 = Pb + (size_t)(fbase + TUP[t][2]) * 6912 + w * 3456 + 2304;
  const float* bias = w ? bv : bk;
  float v[6];
  float sum = 0.f, sq = 0.f;
#pragma unroll
  for (int i = 0; i < 6; ++i) {
    int d = tid + i * 192;
    v[i] = bf2f(p0[d]) + bf2f(p1[d]) + bf2f(p2[d]) + bias[d];
    sum += v[i];
    sq += v[i] * v[i];
  }
  int wavei = tid >> 6, lane = tid & 63;
  if (w == 0) {
#pragma unroll
    for (int off = 32; off; off >>= 1) {
      sum += __shfl_down(sum, off);
      sq += __shfl_down(sq, off);
    }
    if (lane == 0) { s1[wavei] = sum; s2[wavei] = sq; }
    __syncthreads();
    float tot = s1[0] + s1[1] + s1[2];
    float tot2 = s2[0] + s2[1] + s2[2];
    float mean = tot * (1.f / OUT_DIM);
    float var = tot2 * (1.f / OUT_DIM) - mean * mean;
    float inv = rsqrtf(var + 1e-5f);
    unsigned short* outp = isq ? (QKb + (size_t)orow * OUT_DIM) : (SKb + (size_t)orow * OUT_DIM);
#pragma unroll
    for (int i = 0; i < 6; ++i) {
      int d = tid + i * 192;
      outp[d] = f2bf((v[i] - mean) * inv * g[d] + bb[d]);
    }
  } else {
    unsigned short* outp = isq ? (QVb + (size_t)orow * OUT_DIM) : (SVb + (size_t)orow * OUT_DIM);
#pragma unroll
    for (int i = 0; i < 6; ++i) outp[tid + i * 192] = f2bf(v[i]);
    if (isq) {
#pragma unroll
      for (int off = 32; off; off >>= 1) sq += __shfl_down(sq, off);
      if (lane == 0) s2[wavei] = sq;
      __syncthreads();
      if (tid == 0) qnorm[orow] = s2[0] + s2[1] + s2[2];
    }
  }
}

// ---------------- SV transpose: SVT[c][d][kk] (zero-padded to 288) ----------------
__global__ __launch_bounds__(256) void k_svt(const unsigned short* __restrict__ SVb,
                                             unsigned short* __restrict__ SVT) {
  __shared__ unsigned short t[32][33];
  int c = blockIdx.z;
  int k0 = blockIdx.x * 32, d0 = blockIdx.y * 32;
  int tx = threadIdx.x, ty = threadIdx.y;
#pragma unroll
  for (int i = 0; i < 4; ++i) {
    int k = k0 + ty + i * 8;
    t[ty + i * 8][tx] = (k < 280) ? SVb[(size_t)(c * 280 + k) * OUT_DIM + d0 + tx] : 0;
  }
  __syncthreads();
#pragma unroll
  for (int i = 0; i < 4; ++i) {
    int d = d0 + ty + i * 8;
    SVT[((size_t)c * OUT_DIM + d) * KC + k0 + tx] = t[tx][ty + i * 8];
  }
}

// ---------------- A@B^T GEMM: scores (fp32 out) or G1 (bf16 class-padded out) ----------------
template <bool BF16OUT>
__global__ __launch_bounds__(256) void k_rowgemm(const unsigned short* __restrict__ Am,
                                                 const unsigned short* __restrict__ Bm,
                                                 float* __restrict__ outf,
                                                 unsigned short* __restrict__ outb,
                                                 float scale) {
  __shared__ short lds[8192];
  int row0 = blockIdx.y * 128, col0 = blockIdx.x * 128;
  f32x4 acc[4][4];
#pragma unroll
  for (int i = 0; i < 4; ++i)
#pragma unroll
    for (int j = 0; j < 4; ++j) acc[i][j] = (f32x4)(0.f);
  mfma_core((const short*)Am + (size_t)row0 * OUT_DIM, OUT_DIM, min(127, QROWS - 1 - row0),
            (const short*)Bm + (size_t)col0 * OUT_DIM, OUT_DIM, min(127, SROWS - 1 - col0),
            OUT_DIM, lds, acc);
  int lane = threadIdx.x & 63, wave = threadIdx.x >> 6;
  int wm = wave & 1, wn = wave >> 1, col = lane & 15, quad = lane >> 4;
#pragma unroll
  for (int i = 0; i < 4; ++i)
#pragma unroll
    for (int r = 0; r < 4; ++r) {
      int gr = row0 + wm * 64 + i * 16 + quad * 4 + r;
      if (gr >= QROWS) continue;
#pragma unroll
      for (int j = 0; j < 4; ++j) {
        int gc = col0 + wn * 64 + j * 16 + col;
        if (gc < SROWS) {
          if (BF16OUT) {
            int c = gc / 280;
            outb[(size_t)gr * AT_STRIDE + gc + c * 8] = f2bf(acc[i][j][r] * scale);
          } else {
            outf[(size_t)gr * SC_STRIDE + gc] = acc[i][j][r] * scale;
          }
        }
      }
    }
}

// ---------------- per-class softmax + fused term2 = <attn, g1> ----------------
__global__ __launch_bounds__(256) void k_softmax(const float* __restrict__ SC,
                                                 const unsigned short* __restrict__ G1b,
                                                 unsigned short* __restrict__ ATb,
                                                 float* __restrict__ T2) {
  int row = blockIdx.x, tid = threadIdx.x;
  const float* p = SC + (size_t)row * SC_STRIDE;
  const unsigned short* g1r = G1b + (size_t)row * AT_STRIDE;
  __shared__ float redm[WAY][4];
  __shared__ float reds[WAY][4];
  __shared__ float redt[WAY][4];
  float v[6], gv[6];
  int cls[6], loc[6];
  float m[WAY];
#pragma unroll
  for (int c = 0; c < WAY; ++c) m[c] = -INFINITY;
#pragma unroll
  for (int it = 0; it < 6; ++it) {
    int colx = it * 256 + tid;
    if (colx < SROWS) {
      v[it] = p[colx];
      int c = colx / 280;
      cls[it] = c; loc[it] = colx - c * 280;
      gv[it] = bf2f(g1r[c * KC + loc[it]]);
      m[c] = fmaxf(m[c], v[it]);
    } else cls[it] = -1;
  }
#pragma unroll
  for (int off = 32; off; off >>= 1)
#pragma unroll
    for (int c = 0; c < WAY; ++c) m[c] = fmaxf(m[c], __shfl_xor(m[c], off));
  int wavei = tid >> 6, lane = tid & 63;
  if (lane == 0)
#pragma unroll
    for (int c = 0; c < WAY; ++c) redm[c][wavei] = m[c];
  __syncthreads();
  float M[WAY];
#pragma unroll
  for (int c = 0; c < WAY; ++c)
    M[c] = fmaxf(fmaxf(redm[c][0], redm[c][1]), fmaxf(redm[c][2], redm[c][3]));
  float s[WAY], t2[WAY];
#pragma unroll
  for (int c = 0; c < WAY; ++c) { s[c] = 0.f; t2[c] = 0.f; }
#pragma unroll
  for (int it = 0; it < 6; ++it)
    if (cls[it] >= 0) {
      v[it] = expf(v[it] - M[cls[it]]);
      s[cls[it]] += v[it];
      t2[cls[it]] += v[it] * gv[it];
    }
#pragma unroll
  for (int off = 32; off; off >>= 1)
#pragma unroll
    for (int c = 0; c < WAY; ++c) {
      s[c] += __shfl_xor(s[c], off);
      t2[c] += __shfl_xor(t2[c], off);
    }
  if (lane == 0)
#pragma unroll
    for (int c = 0; c < WAY; ++c) { reds[c][wavei] = s[c]; redt[c][wavei] = t2[c]; }
  __syncthreads();
  float S[WAY];
#pragma unroll
  for (int c = 0; c < WAY; ++c) S[c] = reds[c][0] + reds[c][1] + reds[c][2] + reds[c][3];
  unsigned short* op = ATb + (size_t)row * AT_STRIDE;
#pragma unroll
  for (int it = 0; it < 6; ++it)
    if (cls[it] >= 0) op[cls[it] * KC + loc[it]] = f2bf(v[it] / S[cls[it]]);
  if (tid < WAY * 8) op[(tid >> 3) * KC + 280 + (tid & 7)] = 0;  // zero pads
  if (tid < WAY) {
    float tt = redt[tid][0] + redt[tid][1] + redt[tid][2] + redt[tid][3];
    T2[(size_t)tid * QROWS + row] = tt / S[tid];
  }
}

// ---------------- proto GEMM + fused ||proto||^2 partial ----------------
__global__ __launch_bounds__(256) void k_proto(const unsigned short* __restrict__ ATb,
                                               const unsigned short* __restrict__ SVT,
                                               float* __restrict__ T3) {
  __shared__ short lds[8192];
  __shared__ float rowsum[128];
  int c = blockIdx.z;
  int row0 = blockIdx.y * 128, d0 = blockIdx.x * 128;
  int tid = threadIdx.x;
  if (tid < 128) rowsum[tid] = 0.f;
  f32x4 acc[4][4];
#pragma unroll
  for (int i = 0; i < 4; ++i)
#pragma unroll
    for (int j = 0; j < 4; ++j) acc[i][j] = (f32x4)(0.f);
  mfma_core((const short*)ATb + (size_t)row0 * AT_STRIDE + c * KC, AT_STRIDE,
            min(127, QROWS - 1 - row0),
            (const short*)SVT + ((size_t)c * OUT_DIM + d0) * KC, KC, 127,
            KC, lds, acc);
  int lane = tid & 63, wave = tid >> 6;
  int wm = wave & 1, quad = lane >> 4, col = lane & 15;
#pragma unroll
  for (int i = 0; i < 4; ++i)
#pragma unroll
    for (int r = 0; r < 4; ++r) {
      float sacc = 0.f;
#pragma unroll
      for (int j = 0; j < 4; ++j) {
        float pj = acc[i][j][r];
        sacc += pj * pj;
      }
#pragma unroll
      for (int mm = 1; mm < 16; mm <<= 1) sacc += __shfl_xor(sacc, mm);
      if (col == 0) atomicAdd(&rowsum[wm * 64 + i * 16 + quad * 4 + r], sacc);
    }
  __syncthreads();
  if (tid < 128) {
    int gr = row0 + tid;
    if (gr < QROWS) atomicAdd(&T3[(size_t)c * QROWS + gr], rowsum[tid]);
  }
}

// ---------------- finalize: out[q][c] = -(sum_t qnorm - 2*T2 + T3)/56 ----------------
__global__ __launch_bounds__(64) void k_final(const float* __restrict__ qnorm,
                                              const float* __restrict__ T2,
                                              const float* __restrict__ T3,
                                              float* __restrict__ out) {
  int bid = blockIdx.x;          // 0..999
  int q = bid / WAY, c = bid % WAY;
  int t = threadIdx.x;
  float p = 0.f;
  if (t < NTUP) {
    int r = q * NTUP + t;
    p = qnorm[r] - 2.f * T2[(size_t)c * QROWS + r] + T3[(size_t)c * QROWS + r];
  }
#pragma unroll
  for (int off = 32; off; off >>= 1) p += __shfl_down(p, off);
  if (t == 0) out[q * WAY + c] = -p * (1.f / NTUP);
}

// ---------------- launch ----------------
extern "C" void kernel_launch(void* const* d_in, const int* in_sizes, int n_in,
                              void* d_out, int out_size, void* d_ws, size_t ws_size,
                              hipStream_t stream) {
  const float* support = (const float*)d_in[0];
  const int* labels = (const int*)d_in[1];
  const float* queries = (const float*)d_in[2];
  const float* Wk = (const float*)d_in[3];
  const float* bk = (const float*)d_in[4];
  const float* Wv = (const float*)d_in[5];
  const float* bv = (const float*)d_in[6];
  const float* ln_g = (const float*)d_in[7];
  const float* ln_b = (const float*)d_in[8];
  float* out = (float*)d_out;
  char* w8 = (char*)d_ws;

  float* PE = (float*)(w8 + PE_OFF);
  unsigned short* APb = (unsigned short*)(w8 + APB_OFF);
  unsigned short* WT = (unsigned short*)(w8 + WT_OFF);
  unsigned short* Pb = (unsigned short*)(w8 + PB_OFF);
  unsigned short* QKb = (unsigned short*)(w8 + QKB_OFF);
  unsigned short* SKb = (unsigned short*)(w8 + SKB_OFF);
  unsigned short* QVb = (unsigned short*)(w8 + QVB_OFF);
  unsigned short* SVb = (unsigned short*)(w8 + SVB_OFF);
  unsigned short* SVT = (unsigned short*)(w8 + SVT_OFF);
  float* SC = (float*)(w8 + SC_OFF);
  unsigned short* G1b = (unsigned short*)(w8 + G1B_OFF);
  unsigned short* ATb = (unsigned short*)(w8 + ATB_OFF);
  float* QNORM = (float*)(w8 + QNORM_OFF);
  float* T2 = (float*)(w8 + T2_OFF);
  float* T3 = (float*)(w8 + T3_OFF);
  int* RANK = (int*)(w8 + RANK_OFF);

  k_init<<<dim3(227), dim3(256), 0, stream>>>(PE, labels, RANK, T3);
  k_add_pe<<<dim3(1800), dim3(256), 0, stream>>>(support, queries, PE, APb);
  k_wt<<<dim3(64, 36, 6), dim3(32, 8), 0, stream>>>(Wk, Wv, WT);
  k_gemm1<<<dim3(54, 15), dim3(256), 0, stream>>>(APb, WT, Pb);
  k_combine<<<dim3(12600, 2), dim3(192), 0, stream>>>(Pb, bk, bv, ln_g, ln_b, RANK,
                                                      SKb, QKb, SVb, QVb, QNORM);
  k_svt<<<dim3(9, 36, 5), dim3(32, 8), 0, stream>>>(SVb, SVT);
  k_rowgemm<false><<<dim3(11, 88), dim3(256), 0, stream>>>(QKb, SKb, SC, nullptr,
                                                           0.029462782549439483f);
  k_rowgemm<true><<<dim3(11, 88), dim3(256), 0, stream>>>(QVb, SVb, nullptr, G1b, 1.0f);
  k_softmax<<<dim3(11200), dim3(256), 0, stream>>>(SC, G1b, ATb, T2);
  k_proto<<<dim3(9, 88, 5), dim3(256), 0, stream>>>(ATb, SVT, T3);
  k_final<<<dim3(1000), dim3(64), 0, stream>>>(QNORM, T2, T3, out);
}

// Round 4
// 513.702 us; speedup vs baseline: 4.8322x; 1.0181x over previous
//
#include <hip/hip_runtime.h>
#include <math.h>

// ---------------- problem constants ----------------
#define SEQ_LEN 8
#define IN_DIM 2048
#define OUT_DIM 1152
#define NTUP 56
#define NSUP 25
#define NQ 200
#define WAY 5
#define SFRAMES 200
#define NFRAMES 1800
#define SROWS 1400
#define QROWS 11200
#define SC_STRIDE 1408   // fp32 scores row stride
#define AT_STRIDE 1440   // bf16 attn/G1 row stride: 5 classes * 288
#define KC 288           // per-class padded K (280 valid + 8 zeros)

typedef __attribute__((ext_vector_type(8))) short short8;
typedef __attribute__((ext_vector_type(4))) float f32x4;

__device__ __constant__ int TUP[NTUP][3] = {
{0,1,2},{0,1,3},{0,1,4},{0,1,5},{0,1,6},{0,1,7},
{0,2,3},{0,2,4},{0,2,5},{0,2,6},{0,2,7},
{0,3,4},{0,3,5},{0,3,6},{0,3,7},
{0,4,5},{0,4,6},{0,4,7},
{0,5,6},{0,5,7},
{0,6,7},
{1,2,3},{1,2,4},{1,2,5},{1,2,6},{1,2,7},
{1,3,4},{1,3,5},{1,3,6},{1,3,7},
{1,4,5},{1,4,6},{1,4,7},
{1,5,6},{1,5,7},
{1,6,7},
{2,3,4},{2,3,5},{2,3,6},{2,3,7},
{2,4,5},{2,4,6},{2,4,7},
{2,5,6},{2,5,7},
{2,6,7},
{3,4,5},{3,4,6},{3,4,7},
{3,5,6},{3,5,7},
{3,6,7},
{4,5,6},{4,5,7},
{4,6,7},
{5,6,7}};

// ---------------- bf16 helpers ----------------
__device__ __forceinline__ unsigned short f2bf(float x) {
  union { float f; unsigned int u; } v; v.f = x;
  unsigned int r = v.u + 0x7fffu + ((v.u >> 16) & 1u);
  return (unsigned short)(r >> 16);
}
__device__ __forceinline__ float bf2f(unsigned short s) {
  union { float f; unsigned int u; } v; v.u = ((unsigned int)s) << 16;
  return v.f;
}

// async 16B global -> LDS
__device__ __forceinline__ void gll16(const void* g, void* l) {
  __builtin_amdgcn_global_load_lds(
      (const __attribute__((address_space(1))) unsigned int*)g,
      (__attribute__((address_space(3))) unsigned int*)l, 16, 0, 0);
}

// ---------------- workspace byte offsets ----------------
#define PE_OFF    0UL                     // f32 [8][2048]
#define APB_OFF   65536UL                 // bf16 [1800][2048]
#define WT_OFF    7438336UL               // bf16 [6912][2048]
#define PB_OFF    35749888UL              // bf16 [1800][6912]
#define QKB_OFF   60633088UL              // bf16 [11200][1152]
#define SKB_OFF   86437888UL              // bf16 [1400][1152] class-sorted
#define QVB_OFF   89663488UL              // bf16 [11200][1152]
#define SVB_OFF   115468288UL             // bf16 [1400][1152] class-sorted
#define G2_OFF    118693888UL             // bf16 [5][288][288] Gram
#define SC_OFF    122011648UL             // f32  [11200][1408]
#define G1B_OFF   185090048UL             // bf16 [11200][1440] class-padded
#define ATB_OFF   217346048UL             // bf16 [11200][1440] class-padded
#define QNORM_OFF 249602048UL             // f32  [11200]
#define T2_OFF    249646848UL             // f32  [5][11200]
#define T3_OFF    249870848UL             // f32  [5][11200]
#define RANK_OFF  250094848UL             // i32  [25]

// ---------------- init: PE table + rank + zero TERM3 ----------------
__global__ void k_init(float* __restrict__ pe, const int* __restrict__ labels,
                       int* __restrict__ rank, float* __restrict__ t3) {
  int b = blockIdx.x, tid = threadIdx.x;
  if (b < SEQ_LEN) {
    const float c0 = -logf(10000.0f) / (float)IN_DIM;
    for (int i = tid; i < IN_DIM / 2; i += blockDim.x) {
      float dt = expf((float)(2 * i) * c0);
      float arg = (float)b * dt;
      pe[b * IN_DIM + 2 * i]     = sinf(arg) * 0.1f;
      pe[b * IN_DIM + 2 * i + 1] = cosf(arg) * 0.1f;
    }
  } else {
    int idx = (b - 8) * 256 + tid;
    if (idx < WAY * QROWS) t3[idx] = 0.f;
    if (b == 8 && tid == 0) {
      for (int s = 0; s < NSUP; ++s) {
        int r = 0;
        for (int s2 = 0; s2 < NSUP; ++s2)
          r += (labels[s2] < labels[s]) || (labels[s2] == labels[s] && s2 < s);
        rank[s] = r;
      }
    }
  }
}

// ---------------- A' = bf16(X + PE) ----------------
__global__ __launch_bounds__(256) void k_add_pe(const float* __restrict__ S,
                                                const float* __restrict__ Q,
                                                const float* __restrict__ pe,
                                                unsigned short* __restrict__ APb) {
  int idx = blockIdx.x * 256 + threadIdx.x;
  int frame = idx >> 8;
  int e8 = (idx & 255) * 8;
  int pos = frame & 7;
  const float* src = (frame < SFRAMES) ? (S + (size_t)frame * IN_DIM + e8)
                                       : (Q + (size_t)(frame - SFRAMES) * IN_DIM + e8);
  const float* pp = pe + (size_t)pos * IN_DIM + e8;
  float4 x0 = ((const float4*)src)[0], x1 = ((const float4*)src)[1];
  float4 p0 = ((const float4*)pp)[0], p1 = ((const float4*)pp)[1];
  short8 o;
  o[0] = (short)f2bf(x0.x + p0.x); o[1] = (short)f2bf(x0.y + p0.y);
  o[2] = (short)f2bf(x0.z + p0.z); o[3] = (short)f2bf(x0.w + p0.w);
  o[4] = (short)f2bf(x1.x + p1.x); o[5] = (short)f2bf(x1.y + p1.y);
  o[6] = (short)f2bf(x1.z + p1.z); o[7] = (short)f2bf(x1.w + p1.w);
  *(short8*)(APb + (size_t)frame * IN_DIM + e8) = o;
}

// ---------------- weight transpose+convert  WT[col][k] ----------------
__global__ __launch_bounds__(256) void k_wt(const float* __restrict__ Wk,
                                            const float* __restrict__ Wv,
                                            unsigned short* __restrict__ WT) {
  __shared__ float t[32][33];
  int z = blockIdx.z; int w = z / 3, j = z % 3;
  const float* W = w ? Wv : Wk;
  int k0 = blockIdx.x * 32, d0 = blockIdx.y * 32;
  int tx = threadIdx.x, ty = threadIdx.y;
#pragma unroll
  for (int i = 0; i < 4; ++i) {
    int k = k0 + ty + i * 8;
    t[ty + i * 8][tx] = W[(size_t)(j * IN_DIM + k) * OUT_DIM + d0 + tx];
  }
  __syncthreads();
  int colbase = w * 3456 + j * 1152 + d0;
#pragma unroll
  for (int i = 0; i < 4; ++i) {
    int d = ty + i * 8;
    WT[(size_t)(colbase + d) * IN_DIM + k0 + tx] = f2bf(t[tx][d]);
  }
}

// ---------------- MFMA GEMM core (m97 structure) ----------------
__device__ __forceinline__ void mfma_core(const short* __restrict__ A, int lda, int maxA,
                                          const short* __restrict__ B, int ldb, int maxB,
                                          int K, short* lds, f32x4 (&acc)[4][4]) {
  int tid = threadIdx.x;
  int lane = tid & 63, wave = tid >> 6;
  int wm = wave & 1, wn = wave >> 1;
  int col = lane & 15, quad = lane >> 4;
  short* As = lds;           // [128][32]
  short* Bs = lds + 4096;    // [128][32]
  int s0 = tid, s1 = tid + 256;
  int r0 = s0 >> 2, r1 = s1 >> 2;
  int o0 = (s0 & 3) * 8, o1 = (s1 & 3) * 8;
  const short* a0p = A + (size_t)min(r0, maxA) * lda + o0;
  const short* a1p = A + (size_t)min(r1, maxA) * lda + o1;
  const short* b0p = B + (size_t)min(r0, maxB) * ldb + o0;
  const short* b1p = B + (size_t)min(r1, maxB) * ldb + o1;
  short* la0 = As + s0 * 8; short* la1 = As + s1 * 8;
  short* lb0 = Bs + s0 * 8; short* lb1 = Bs + s1 * 8;

  for (int k0 = 0; k0 < K; k0 += 32) {
    gll16(a0p + k0, la0);
    gll16(a1p + k0, la1);
    gll16(b0p + k0, lb0);
    gll16(b1p + k0, lb1);
    __syncthreads();
    short8 af[4], bf[4];
#pragma unroll
    for (int i = 0; i < 4; ++i)
      af[i] = *(const short8*)(As + (wm * 64 + i * 16 + col) * 32 + quad * 8);
#pragma unroll
    for (int j = 0; j < 4; ++j)
      bf[j] = *(const short8*)(Bs + (wn * 64 + j * 16 + col) * 32 + quad * 8);
#pragma unroll
    for (int i = 0; i < 4; ++i)
#pragma unroll
      for (int j = 0; j < 4; ++j)
        acc[i][j] = __builtin_amdgcn_mfma_f32_16x16x32_bf16(af[i], bf[j], acc[i][j], 0, 0, 0);
    __syncthreads();
  }
}

// ---------------- GEMM1: Pb[1800][6912] = APb @ WT^T ----------------
__global__ __launch_bounds__(256) void k_gemm1(const unsigned short* __restrict__ APb,
                                               const unsigned short* __restrict__ WT,
                                               unsigned short* __restrict__ Pb) {
  __shared__ short lds[8192];
  int row0 = blockIdx.y * 128, col0 = blockIdx.x * 128;
  f32x4 acc[4][4];
#pragma unroll
  for (int i = 0; i < 4; ++i)
#pragma unroll
    for (int j = 0; j < 4; ++j) acc[i][j] = (f32x4)(0.f);
  mfma_core((const short*)APb + (size_t)row0 * IN_DIM, IN_DIM, min(127, NFRAMES - 1 - row0),
            (const short*)WT + (size_t)col0 * IN_DIM, IN_DIM, 127,
            IN_DIM, lds, acc);
  int lane = threadIdx.x & 63, wave = threadIdx.x >> 6;
  int wm = wave & 1, wn = wave >> 1, col = lane & 15, quad = lane >> 4;
#pragma unroll
  for (int i = 0; i < 4; ++i)
#pragma unroll
    for (int r = 0; r < 4; ++r) {
      int gr = row0 + wm * 64 + i * 16 + quad * 4 + r;
      if (gr >= NFRAMES) continue;
#pragma unroll
      for (int j = 0; j < 4; ++j)
        Pb[(size_t)gr * 6912 + col0 + wn * 64 + j * 16 + col] = f2bf(acc[i][j][r]);
    }
}

// ---------------- combine: sum 3 frame projections, +bias, LN(k), qnorm(v) ----------------
__global__ __launch_bounds__(192) void k_combine(const unsigned short* __restrict__ Pb,
                                                 const float* __restrict__ bk,
                                                 const float* __restrict__ bv,
                                                 const float* __restrict__ g,
                                                 const float* __restrict__ bb,
                                                 const int* __restrict__ rank,
                                                 unsigned short* __restrict__ SKb,
                                                 unsigned short* __restrict__ QKb,
                                                 unsigned short* __restrict__ SVb,
                                                 unsigned short* __restrict__ QVb,
                                                 float* __restrict__ qnorm) {
  __shared__ float s1[3], s2[3];
  int row = blockIdx.x;     // 0..12599
  int w = blockIdx.y;       // 0 = k, 1 = v
  int tid = threadIdx.x;
  bool isq = row >= SROWS;
  int r = isq ? row - SROWS : row;
  int n = r / NTUP, t = r - n * NTUP;
  int orow = isq ? r : (rank[n] * NTUP + t);
  int fbase = (isq ? SFRAMES + n * SEQ_LEN : n * SEQ_LEN);
  const unsigned short* p0 = Pb + (size_t)(fbase + TUP[t][0]) * 6912 + w * 3456;
  const unsigned short* p1 = Pb + (size_t)(fbase + TUP[t][1]) * 6912 + w * 3456 + 1152;
  const unsigned short* p2 = Pb + (size_t)(fbase + TUP[t][2]) * 6912 + w * 3456 + 2304;
  const float* bias = w ? bv : bk;
  float v[6];
  float sum = 0.f, sq = 0.f;
#pragma unroll
  for (int i = 0; i < 6; ++i) {
    int d = tid + i * 192;
    v[i] = bf2f(p0[d]) + bf2f(p1[d]) + bf2f(p2[d]) + bias[d];
    sum += v[i];
    sq += v[i] * v[i];
  }
  int wavei = tid >> 6, lane = tid & 63;
  if (w == 0) {
#pragma unroll
    for (int off = 32; off; off >>= 1) {
      sum += __shfl_down(sum, off);
      sq += __shfl_down(sq, off);
    }
    if (lane == 0) { s1[wavei] = sum; s2[wavei] = sq; }
    __syncthreads();
    float tot = s1[0] + s1[1] + s1[2];
    float tot2 = s2[0] + s2[1] + s2[2];
    float mean = tot * (1.f / OUT_DIM);
    float var = tot2 * (1.f / OUT_DIM) - mean * mean;
    float inv = rsqrtf(var + 1e-5f);
    unsigned short* outp = isq ? (QKb + (size_t)orow * OUT_DIM) : (SKb + (size_t)orow * OUT_DIM);
#pragma unroll
    for (int i = 0; i < 6; ++i) {
      int d = tid + i * 192;
      outp[d] = f2bf((v[i] - mean) * inv * g[d] + bb[d]);
    }
  } else {
    unsigned short* outp = isq ? (QVb + (size_t)orow * OUT_DIM) : (SVb + (size_t)orow * OUT_DIM);
#pragma unroll
    for (int i = 0; i < 6; ++i) outp[tid + i * 192] = f2bf(v[i]);
    if (isq) {
#pragma unroll
      for (int off = 32; off; off >>= 1) sq += __shfl_down(sq, off);
      if (lane == 0) s2[wavei] = sq;
      __syncthreads();
      if (tid == 0) qnorm[orow] = s2[0] + s2[1] + s2[2];
    }
  }
}

// ---------------- per-class Gram: G2[c] = SV_c @ SV_c^T (bf16, padded 288) ----------------
__global__ __launch_bounds__(256) void k_g2(const unsigned short* __restrict__ SVb,
                                            unsigned short* __restrict__ G2) {
  __shared__ short lds[8192];
  int c = blockIdx.z;
  int i0 = blockIdx.y * 128, j0 = blockIdx.x * 128;
  f32x4 acc[4][4];
#pragma unroll
  for (int i = 0; i < 4; ++i)
#pragma unroll
    for (int j = 0; j < 4; ++j) acc[i][j] = (f32x4)(0.f);
  const short* base = (const short*)SVb + (size_t)c * 280 * OUT_DIM;
  mfma_core(base + (size_t)i0 * OUT_DIM, OUT_DIM, min(127, 279 - i0),
            base + (size_t)j0 * OUT_DIM, OUT_DIM, min(127, 279 - j0),
            OUT_DIM, lds, acc);
  int lane = threadIdx.x & 63, wave = threadIdx.x >> 6;
  int wm = wave & 1, wn = wave >> 1, col = lane & 15, quad = lane >> 4;
  unsigned short* g2c = G2 + (size_t)c * KC * KC;
#pragma unroll
  for (int i = 0; i < 4; ++i)
#pragma unroll
    for (int r = 0; r < 4; ++r) {
      int gi = i0 + wm * 64 + i * 16 + quad * 4 + r;
      if (gi >= KC) continue;
#pragma unroll
      for (int j = 0; j < 4; ++j) {
        int gj = j0 + wn * 64 + j * 16 + col;
        if (gj < KC) g2c[(size_t)gi * KC + gj] = f2bf(acc[i][j][r]);
      }
    }
}

// ---------------- merged A@B^T GEMM: z=0 scores (fp32), z=1 G1 (bf16 class-padded) ----------------
__global__ __launch_bounds__(256) void k_rowgemm(const unsigned short* __restrict__ QKb,
                                                 const unsigned short* __restrict__ SKb,
                                                 const unsigned short* __restrict__ QVb,
                                                 const unsigned short* __restrict__ SVb,
                                                 float* __restrict__ SC,
                                                 unsigned short* __restrict__ G1b) {
  __shared__ short lds[8192];
  bool g1 = blockIdx.z != 0;
  const unsigned short* Am = g1 ? QVb : QKb;
  const unsigned short* Bm = g1 ? SVb : SKb;
  int row0 = blockIdx.y * 128, col0 = blockIdx.x * 128;
  f32x4 acc[4][4];
#pragma unroll
  for (int i = 0; i < 4; ++i)
#pragma unroll
    for (int j = 0; j < 4; ++j) acc[i][j] = (f32x4)(0.f);
  mfma_core((const short*)Am + (size_t)row0 * OUT_DIM, OUT_DIM, min(127, QROWS - 1 - row0),
            (const short*)Bm + (size_t)col0 * OUT_DIM, OUT_DIM, min(127, SROWS - 1 - col0),
            OUT_DIM, lds, acc);
  int lane = threadIdx.x & 63, wave = threadIdx.x >> 6;
  int wm = wave & 1, wn = wave >> 1, col = lane & 15, quad = lane >> 4;
  const float scale = 0.029462782549439483f;  // 1/sqrt(1152)
#pragma unroll
  for (int i = 0; i < 4; ++i)
#pragma unroll
    for (int r = 0; r < 4; ++r) {
      int gr = row0 + wm * 64 + i * 16 + quad * 4 + r;
      if (gr >= QROWS) continue;
#pragma unroll
      for (int j = 0; j < 4; ++j) {
        int gc = col0 + wn * 64 + j * 16 + col;
        if (gc < SROWS) {
          if (g1) {
            int c = gc / 280;
            G1b[(size_t)gr * AT_STRIDE + gc + c * 8] = f2bf(acc[i][j][r]);
          } else {
            SC[(size_t)gr * SC_STRIDE + gc] = acc[i][j][r] * scale;
          }
        }
      }
    }
}

// ---------------- per-class softmax + fused term2 = <attn, g1> ----------------
__global__ __launch_bounds__(256) void k_softmax(const float* __restrict__ SC,
                                                 const unsigned short* __restrict__ G1b,
                                                 unsigned short* __restrict__ ATb,
                                                 float* __restrict__ T2) {
  int row = blockIdx.x, tid = threadIdx.x;
  const float* p = SC + (size_t)row * SC_STRIDE;
  const unsigned short* g1r = G1b + (size_t)row * AT_STRIDE;
  __shared__ float redm[WAY][4];
  __shared__ float reds[WAY][4];
  __shared__ float redt[WAY][4];
  float v[6], gv[6];
  int cls[6], loc[6];
  float m[WAY];
#pragma unroll
  for (int c = 0; c < WAY; ++c) m[c] = -INFINITY;
#pragma unroll
  for (int it = 0; it < 6; ++it) {
    int colx = it * 256 + tid;
    if (colx < SROWS) {
      v[it] = p[colx];
      int c = colx / 280;
      cls[it] = c; loc[it] = colx - c * 280;
      gv[it] = bf2f(g1r[c * KC + loc[it]]);
      m[c] = fmaxf(m[c], v[it]);
    } else cls[it] = -1;
  }
#pragma unroll
  for (int off = 32; off; off >>= 1)
#pragma unroll
    for (int c = 0; c < WAY; ++c) m[c] = fmaxf(m[c], __shfl_xor(m[c], off));
  int wavei = tid >> 6, lane = tid & 63;
  if (lane == 0)
#pragma unroll
    for (int c = 0; c < WAY; ++c) redm[c][wavei] = m[c];
  __syncthreads();
  float M[WAY];
#pragma unroll
  for (int c = 0; c < WAY; ++c)
    M[c] = fmaxf(fmaxf(redm[c][0], redm[c][1]), fmaxf(redm[c][2], redm[c][3]));
  float s[WAY], t2[WAY];
#pragma unroll
  for (int c = 0; c < WAY; ++c) { s[c] = 0.f; t2[c] = 0.f; }
#pragma unroll
  for (int it = 0; it < 6; ++it)
    if (cls[it] >= 0) {
      v[it] = expf(v[it] - M[cls[it]]);
      s[cls[it]] += v[it];
      t2[cls[it]] += v[it] * gv[it];
    }
#pragma unroll
  for (int off = 32; off; off >>= 1)
#pragma unroll
    for (int c = 0; c < WAY; ++c) {
      s[c] += __shfl_xor(s[c], off);
      t2[c] += __shfl_xor(t2[c], off);
    }
  if (lane == 0)
#pragma unroll
    for (int c = 0; c < WAY; ++c) { reds[c][wavei] = s[c]; redt[c][wavei] = t2[c]; }
  __syncthreads();
  float S[WAY];
#pragma unroll
  for (int c = 0; c < WAY; ++c) S[c] = reds[c][0] + reds[c][1] + reds[c][2] + reds[c][3];
  unsigned short* op = ATb + (size_t)row * AT_STRIDE;
#pragma unroll
  for (int it = 0; it < 6; ++it)
    if (cls[it] >= 0) op[cls[it] * KC + loc[it]] = f2bf(v[it] / S[cls[it]]);
  if (tid < WAY * 8) op[(tid >> 3) * KC + 280 + (tid & 7)] = 0;  // zero pads
  if (tid < WAY) {
    float tt = redt[tid][0] + redt[tid][1] + redt[tid][2] + redt[tid][3];
    T2[(size_t)tid * QROWS + row] = tt / S[tid];
  }
}

// ---------------- B2 = attn_c @ G2_c with fused T3 rowdot: T3 = a^T G2 a ----------------
__global__ __launch_bounds__(256) void k_b2t3(const unsigned short* __restrict__ ATb,
                                              const unsigned short* __restrict__ G2,
                                              float* __restrict__ T3) {
  __shared__ short lds[8192];
  __shared__ float rowsum[128];
  int c = blockIdx.z;
  int row0 = blockIdx.y * 128, j0 = blockIdx.x * 128;
  int tid = threadIdx.x;
  if (tid < 128) rowsum[tid] = 0.f;
  f32x4 acc[4][4];
#pragma unroll
  for (int i = 0; i < 4; ++i)
#pragma unroll
    for (int j = 0; j < 4; ++j) acc[i][j] = (f32x4)(0.f);
  mfma_core((const short*)ATb + (size_t)row0 * AT_STRIDE + c * KC, AT_STRIDE,
            min(127, QROWS - 1 - row0),
            (const short*)G2 + (size_t)c * KC * KC + (size_t)j0 * KC, KC,
            min(127, KC - 1 - j0),
            KC, lds, acc);
  int lane = tid & 63, wave = tid >> 6;
  int wm = wave & 1, wn = wave >> 1, quad = lane >> 4, col = lane & 15;
#pragma unroll
  for (int i = 0; i < 4; ++i)
#pragma unroll
    for (int r = 0; r < 4; ++r) {
      int rl = wm * 64 + i * 16 + quad * 4 + r;
      int gr = row0 + rl;
      float sacc = 0.f;
      if (gr < QROWS) {
        const unsigned short* ar = ATb + (size_t)gr * AT_STRIDE + c * KC;
#pragma unroll
        for (int j = 0; j < 4; ++j) {
          int gj = j0 + wn * 64 + j * 16 + col;
          if (gj < KC) sacc += bf2f(ar[gj]) * acc[i][j][r];
        }
      }
#pragma unroll
      for (int mm = 1; mm < 16; mm <<= 1) sacc += __shfl_xor(sacc, mm);
      if (col == 0) atomicAdd(&rowsum[rl], sacc);
    }
  __syncthreads();
  if (tid < 128) {
    int gr = row0 + tid;
    if (gr < QROWS) atomicAdd(&T3[(size_t)c * QROWS + gr], rowsum[tid]);
  }
}

// ---------------- finalize: out[q][c] = -(sum_t qnorm - 2*T2 + T3)/56 ----------------
__global__ __launch_bounds__(64) void k_final(const float* __restrict__ qnorm,
                                              const float* __restrict__ T2,
                                              const float* __restrict__ T3,
                                              float* __restrict__ out) {
  int bid = blockIdx.x;          // 0..999
  int q = bid / WAY, c = bid % WAY;
  int t = threadIdx.x;
  float p = 0.f;
  if (t < NTUP) {
    int r = q * NTUP + t;
    p = qnorm[r] - 2.f * T2[(size_t)c * QROWS + r] + T3[(size_t)c * QROWS + r];
  }
#pragma unroll
  for (int off = 32; off; off >>= 1) p += __shfl_down(p, off);
  if (t == 0) out[q * WAY + c] = -p * (1.f / NTUP);
}

// ---------------- launch ----------------
extern "C" void kernel_launch(void* const* d_in, const int* in_sizes, int n_in,
                              void* d_out, int out_size, void* d_ws, size_t ws_size,
                              hipStream_t stream) {
  const float* support = (const float*)d_in[0];
  const int* labels = (const int*)d_in[1];
  const float* queries = (const float*)d_in[2];
  const float* Wk = (const float*)d_in[3];
  const float* bk = (const float*)d_in[4];
  const float* Wv = (const float*)d_in[5];
  const float* bv = (const float*)d_in[6];
  const float* ln_g = (const float*)d_in[7];
  const float* ln_b = (const float*)d_in[8];
  float* out = (float*)d_out;
  char* w8 = (char*)d_ws;

  float* PE = (float*)(w8 + PE_OFF);
  unsigned short* APb = (unsigned short*)(w8 + APB_OFF);
  unsigned short* WT = (unsigned short*)(w8 + WT_OFF);
  unsigned short* Pb = (unsigned short*)(w8 + PB_OFF);
  unsigned short* QKb = (unsigned short*)(w8 + QKB_OFF);
  unsigned short* SKb = (unsigned short*)(w8 + SKB_OFF);
  unsigned short* QVb = (unsigned short*)(w8 + QVB_OFF);
  unsigned short* SVb = (unsigned short*)(w8 + SVB_OFF);
  unsigned short* G2 = (unsigned short*)(w8 + G2_OFF);
  float* SC = (float*)(w8 + SC_OFF);
  unsigned short* G1b = (unsigned short*)(w8 + G1B_OFF);
  unsigned short* ATb = (unsigned short*)(w8 + ATB_OFF);
  float* QNORM = (float*)(w8 + QNORM_OFF);
  float* T2 = (float*)(w8 + T2_OFF);
  float* T3 = (float*)(w8 + T3_OFF);
  int* RANK = (int*)(w8 + RANK_OFF);

  k_init<<<dim3(227), dim3(256), 0, stream>>>(PE, labels, RANK, T3);
  k_add_pe<<<dim3(1800), dim3(256), 0, stream>>>(support, queries, PE, APb);
  k_wt<<<dim3(64, 36, 6), dim3(32, 8), 0, stream>>>(Wk, Wv, WT);
  k_gemm1<<<dim3(54, 15), dim3(256), 0, stream>>>(APb, WT, Pb);
  k_combine<<<dim3(12600, 2), dim3(192), 0, stream>>>(Pb, bk, bv, ln_g, ln_b, RANK,
                                                      SKb, QKb, SVb, QVb, QNORM);
  k_g2<<<dim3(3, 3, 5), dim3(256), 0, stream>>>(SVb, G2);
  k_rowgemm<<<dim3(11, 88, 2), dim3(256), 0, stream>>>(QKb, SKb, QVb, SVb, SC, G1b);
  k_softmax<<<dim3(11200), dim3(256), 0, stream>>>(SC, G1b, ATb, T2);
  k_b2t3<<<dim3(3, 88, 5), dim3(256), 0, stream>>>(ATb, G2, T3);
  k_final<<<dim3(1000), dim3(64), 0, stream>>>(QNORM, T2, T3, out);
}

// Round 5
// 473.782 us; speedup vs baseline: 5.2393x; 1.0843x over previous
//
#include <hip/hip_runtime.h>
#include <math.h>

// ---------------- problem constants ----------------
#define SEQ_LEN 8
#define IN_DIM 2048
#define OUT_DIM 1152
#define NTUP 56
#define NSUP 25
#define NQ 200
#define WAY 5
#define SFRAMES 200
#define NFRAMES 1800
#define SROWS 1400
#define QROWS 11200
#define SC_STRIDE 1408   // fp32 scores row stride
#define AT_STRIDE 1440   // bf16 attn/G1 row stride: 5 classes * 288
#define KC 288           // per-class padded K (280 valid + 8 zeros)

typedef __attribute__((ext_vector_type(8))) short short8;
typedef __attribute__((ext_vector_type(4))) float f32x4;

__device__ __constant__ int TUP[NTUP][3] = {
{0,1,2},{0,1,3},{0,1,4},{0,1,5},{0,1,6},{0,1,7},
{0,2,3},{0,2,4},{0,2,5},{0,2,6},{0,2,7},
{0,3,4},{0,3,5},{0,3,6},{0,3,7},
{0,4,5},{0,4,6},{0,4,7},
{0,5,6},{0,5,7},
{0,6,7},
{1,2,3},{1,2,4},{1,2,5},{1,2,6},{1,2,7},
{1,3,4},{1,3,5},{1,3,6},{1,3,7},
{1,4,5},{1,4,6},{1,4,7},
{1,5,6},{1,5,7},
{1,6,7},
{2,3,4},{2,3,5},{2,3,6},{2,3,7},
{2,4,5},{2,4,6},{2,4,7},
{2,5,6},{2,5,7},
{2,6,7},
{3,4,5},{3,4,6},{3,4,7},
{3,5,6},{3,5,7},
{3,6,7},
{4,5,6},{4,5,7},
{4,6,7},
{5,6,7}};

// ---------------- bf16 helpers ----------------
__device__ __forceinline__ unsigned short f2bf(float x) {
  union { float f; unsigned int u; } v; v.f = x;
  unsigned int r = v.u + 0x7fffu + ((v.u >> 16) & 1u);
  return (unsigned short)(r >> 16);
}
__device__ __forceinline__ float bf2f(unsigned short s) {
  union { float f; unsigned int u; } v; v.u = ((unsigned int)s) << 16;
  return v.f;
}

// async 16B global -> LDS
__device__ __forceinline__ void gll16(const void* g, void* l) {
  __builtin_amdgcn_global_load_lds(
      (const __attribute__((address_space(1))) unsigned int*)g,
      (__attribute__((address_space(3))) unsigned int*)l, 16, 0, 0);
}

// ---------------- workspace byte offsets ----------------
#define PE_OFF    0UL                     // f32 [8][2048]
#define APB_OFF   65536UL                 // bf16 [1800][2048]
#define WT_OFF    7438336UL               // bf16 [6912][2048]
#define PB_OFF    35749888UL              // bf16 [1800][6912]
#define QKB_OFF   60633088UL              // bf16 [11200][1152]
#define SKB_OFF   86437888UL              // bf16 [1400][1152] class-sorted
#define QVB_OFF   89663488UL              // bf16 [11200][1152]
#define SVB_OFF   115468288UL             // bf16 [1400][1152] class-sorted
#define G2_OFF    118693888UL             // bf16 [5][288][288] Gram
#define SC_OFF    122011648UL             // f32  [11200][1408]
#define G1B_OFF   185090048UL             // bf16 [11200][1440] class-padded
#define ATB_OFF   217346048UL             // bf16 [11200][1440] class-padded
#define QNORM_OFF 249602048UL             // f32  [11200]
#define T2_OFF    249646848UL             // f32  [5][11200]
#define T3_OFF    249870848UL             // f32  [5][11200]
#define RANK_OFF  250094848UL             // i32  [25]

// ---------------- init: PE table + rank + zero TERM3 ----------------
__global__ void k_init(float* __restrict__ pe, const int* __restrict__ labels,
                       int* __restrict__ rank, float* __restrict__ t3) {
  int b = blockIdx.x, tid = threadIdx.x;
  if (b < SEQ_LEN) {
    const float c0 = -logf(10000.0f) / (float)IN_DIM;
    for (int i = tid; i < IN_DIM / 2; i += blockDim.x) {
      float dt = expf((float)(2 * i) * c0);
      float arg = (float)b * dt;
      pe[b * IN_DIM + 2 * i]     = sinf(arg) * 0.1f;
      pe[b * IN_DIM + 2 * i + 1] = cosf(arg) * 0.1f;
    }
  } else {
    int idx = (b - 8) * 256 + tid;
    if (idx < WAY * QROWS) t3[idx] = 0.f;
    if (b == 8 && tid == 0) {
      for (int s = 0; s < NSUP; ++s) {
        int r = 0;
        for (int s2 = 0; s2 < NSUP; ++s2)
          r += (labels[s2] < labels[s]) || (labels[s2] == labels[s] && s2 < s);
        rank[s] = r;
      }
    }
  }
}

// ---------------- A' = bf16(X + PE) ----------------
__global__ __launch_bounds__(256) void k_add_pe(const float* __restrict__ S,
                                                const float* __restrict__ Q,
                                                const float* __restrict__ pe,
                                                unsigned short* __restrict__ APb) {
  int idx = blockIdx.x * 256 + threadIdx.x;
  int frame = idx >> 8;
  int e8 = (idx & 255) * 8;
  int pos = frame & 7;
  const float* src = (frame < SFRAMES) ? (S + (size_t)frame * IN_DIM + e8)
                                       : (Q + (size_t)(frame - SFRAMES) * IN_DIM + e8);
  const float* pp = pe + (size_t)pos * IN_DIM + e8;
  float4 x0 = ((const float4*)src)[0], x1 = ((const float4*)src)[1];
  float4 p0 = ((const float4*)pp)[0], p1 = ((const float4*)pp)[1];
  short8 o;
  o[0] = (short)f2bf(x0.x + p0.x); o[1] = (short)f2bf(x0.y + p0.y);
  o[2] = (short)f2bf(x0.z + p0.z); o[3] = (short)f2bf(x0.w + p0.w);
  o[4] = (short)f2bf(x1.x + p1.x); o[5] = (short)f2bf(x1.y + p1.y);
  o[6] = (short)f2bf(x1.z + p1.z); o[7] = (short)f2bf(x1.w + p1.w);
  *(short8*)(APb + (size_t)frame * IN_DIM + e8) = o;
}

// ---------------- weight transpose+convert  WT[col][k] ----------------
__global__ __launch_bounds__(256) void k_wt(const float* __restrict__ Wk,
                                            const float* __restrict__ Wv,
                                            unsigned short* __restrict__ WT) {
  __shared__ float t[32][33];
  int z = blockIdx.z; int w = z / 3, j = z % 3;
  const float* W = w ? Wv : Wk;
  int k0 = blockIdx.x * 32, d0 = blockIdx.y * 32;
  int tx = threadIdx.x, ty = threadIdx.y;
#pragma unroll
  for (int i = 0; i < 4; ++i) {
    int k = k0 + ty + i * 8;
    t[ty + i * 8][tx] = W[(size_t)(j * IN_DIM + k) * OUT_DIM + d0 + tx];
  }
  __syncthreads();
  int colbase = w * 3456 + j * 1152 + d0;
#pragma unroll
  for (int i = 0; i < 4; ++i) {
    int d = ty + i * 8;
    WT[(size_t)(colbase + d) * IN_DIM + k0 + tx] = f2bf(t[tx][d]);
  }
}

// ---------------- MFMA GEMM core (m97 structure) ----------------
__device__ __forceinline__ void mfma_core(const short* __restrict__ A, int lda, int maxA,
                                          const short* __restrict__ B, int ldb, int maxB,
                                          int K, short* lds, f32x4 (&acc)[4][4]) {
  int tid = threadIdx.x;
  int lane = tid & 63, wave = tid >> 6;
  int wm = wave & 1, wn = wave >> 1;
  int col = lane & 15, quad = lane >> 4;
  short* As = lds;           // [128][32]
  short* Bs = lds + 4096;    // [128][32]
  int s0 = tid, s1 = tid + 256;
  int r0 = s0 >> 2, r1 = s1 >> 2;
  int o0 = (s0 & 3) * 8, o1 = (s1 & 3) * 8;
  const short* a0p = A + (size_t)min(r0, maxA) * lda + o0;
  const short* a1p = A + (size_t)min(r1, maxA) * lda + o1;
  const short* b0p = B + (size_t)min(r0, maxB) * ldb + o0;
  const short* b1p = B + (size_t)min(r1, maxB) * ldb + o1;
  short* la0 = As + s0 * 8; short* la1 = As + s1 * 8;
  short* lb0 = Bs + s0 * 8; short* lb1 = Bs + s1 * 8;

  for (int k0 = 0; k0 < K; k0 += 32) {
    gll16(a0p + k0, la0);
    gll16(a1p + k0, la1);
    gll16(b0p + k0, lb0);
    gll16(b1p + k0, lb1);
    __syncthreads();
    short8 af[4], bf[4];
#pragma unroll
    for (int i = 0; i < 4; ++i)
      af[i] = *(const short8*)(As + (wm * 64 + i * 16 + col) * 32 + quad * 8);
#pragma unroll
    for (int j = 0; j < 4; ++j)
      bf[j] = *(const short8*)(Bs + (wn * 64 + j * 16 + col) * 32 + quad * 8);
#pragma unroll
    for (int i = 0; i < 4; ++i)
#pragma unroll
      for (int j = 0; j < 4; ++j)
        acc[i][j] = __builtin_amdgcn_mfma_f32_16x16x32_bf16(af[i], bf[j], acc[i][j], 0, 0, 0);
    __syncthreads();
  }
}

// ---------------- GEMM1: Pb[1800][6912] = APb @ WT^T ----------------
__global__ __launch_bounds__(256) void k_gemm1(const unsigned short* __restrict__ APb,
                                               const unsigned short* __restrict__ WT,
                                               unsigned short* __restrict__ Pb) {
  __shared__ short lds[8192];
  int row0 = blockIdx.y * 128, col0 = blockIdx.x * 128;
  f32x4 acc[4][4];
#pragma unroll
  for (int i = 0; i < 4; ++i)
#pragma unroll
    for (int j = 0; j < 4; ++j) acc[i][j] = (f32x4)(0.f);
  mfma_core((const short*)APb + (size_t)row0 * IN_DIM, IN_DIM, min(127, NFRAMES - 1 - row0),
            (const short*)WT + (size_t)col0 * IN_DIM, IN_DIM, 127,
            IN_DIM, lds, acc);
  int lane = threadIdx.x & 63, wave = threadIdx.x >> 6;
  int wm = wave & 1, wn = wave >> 1, col = lane & 15, quad = lane >> 4;
#pragma unroll
  for (int i = 0; i < 4; ++i)
#pragma unroll
    for (int r = 0; r < 4; ++r) {
      int gr = row0 + wm * 64 + i * 16 + quad * 4 + r;
      if (gr >= NFRAMES) continue;
#pragma unroll
      for (int j = 0; j < 4; ++j)
        Pb[(size_t)gr * 6912 + col0 + wn * 64 + j * 16 + col] = f2bf(acc[i][j][r]);
    }
}

// ---------------- combine: sum 3 frame projections, +bias, LN(k), qnorm(v) ----------------
__global__ __launch_bounds__(192) void k_combine(const unsigned short* __restrict__ Pb,
                                                 const float* __restrict__ bk,
                                                 const float* __restrict__ bv,
                                                 const float* __restrict__ g,
                                                 const float* __restrict__ bb,
                                                 const int* __restrict__ rank,
                                                 unsigned short* __restrict__ SKb,
                                                 unsigned short* __restrict__ QKb,
                                                 unsigned short* __restrict__ SVb,
                                                 unsigned short* __restrict__ QVb,
                                                 float* __restrict__ qnorm) {
  __shared__ float s1[3], s2[3];
  int row = blockIdx.x;     // 0..12599
  int w = blockIdx.y;       // 0 = k, 1 = v
  int tid = threadIdx.x;
  bool isq = row >= SROWS;
  int r = isq ? row - SROWS : row;
  int n = r / NTUP, t = r - n * NTUP;
  int orow = isq ? r : (rank[n] * NTUP + t);
  int fbase = (isq ? SFRAMES + n * SEQ_LEN : n * SEQ_LEN);
  const unsigned short* p0 = Pb + (size_t)(fbase + TUP[t][0]) * 6912 + w * 3456;
  const unsigned short* p1 = Pb + (size_t)(fbase + TUP[t][1]) * 6912 + w * 3456 + 1152;
  const unsigned short* p2 = Pb + (size_t)(fbase + TUP[t][2]) * 6912 + w * 3456 + 2304;
  const float* bias = w ? bv : bk;
  float v[6];
  float sum = 0.f, sq = 0.f;
#pragma unroll
  for (int i = 0; i < 6; ++i) {
    int d = tid + i * 192;
    v[i] = bf2f(p0[d]) + bf2f(p1[d]) + bf2f(p2[d]) + bias[d];
    sum += v[i];
    sq += v[i] * v[i];
  }
  int wavei = tid >> 6, lane = tid & 63;
  if (w == 0) {
#pragma unroll
    for (int off = 32; off; off >>= 1) {
      sum += __shfl_down(sum, off);
      sq += __shfl_down(sq, off);
    }
    if (lane == 0) { s1[wavei] = sum; s2[wavei] = sq; }
    __syncthreads();
    float tot = s1[0] + s1[1] + s1[2];
    float tot2 = s2[0] + s2[1] + s2[2];
    float mean = tot * (1.f / OUT_DIM);
    float var = tot2 * (1.f / OUT_DIM) - mean * mean;
    float inv = rsqrtf(var + 1e-5f);
    unsigned short* outp = isq ? (QKb + (size_t)orow * OUT_DIM) : (SKb + (size_t)orow * OUT_DIM);
#pragma unroll
    for (int i = 0; i < 6; ++i) {
      int d = tid + i * 192;
      outp[d] = f2bf((v[i] - mean) * inv * g[d] + bb[d]);
    }
  } else {
    unsigned short* outp = isq ? (QVb + (size_t)orow * OUT_DIM) : (SVb + (size_t)orow * OUT_DIM);
#pragma unroll
    for (int i = 0; i < 6; ++i) outp[tid + i * 192] = f2bf(v[i]);
    if (isq) {
#pragma unroll
      for (int off = 32; off; off >>= 1) sq += __shfl_down(sq, off);
      if (lane == 0) s2[wavei] = sq;
      __syncthreads();
      if (tid == 0) qnorm[orow] = s2[0] + s2[1] + s2[2];
    }
  }
}

// ---------------- merged: scores / G1 (XCD-swizzled) + per-class Gram G2 tail ----------------
// L in [0,1936): GEMM vs support rows. Delinearize L = (rowGroup*11 + col)*8 + rowSub
// so the 11 col-tiles sharing one A row-tile sit 8 apart (same XCD, consecutive) ->
// A fetched once per row from HBM, B (3.2 MB) resident per-XCD L2.
// L in [1936,1981): G2[c] = SV_c @ SV_c^T (45 blocks).
__global__ __launch_bounds__(256) void k_rowgemm(const unsigned short* __restrict__ QKb,
                                                 const unsigned short* __restrict__ SKb,
                                                 const unsigned short* __restrict__ QVb,
                                                 const unsigned short* __restrict__ SVb,
                                                 float* __restrict__ SC,
                                                 unsigned short* __restrict__ G1b,
                                                 unsigned short* __restrict__ G2) {
  __shared__ short lds[8192];
  int L = blockIdx.x;
  f32x4 acc[4][4];
#pragma unroll
  for (int i = 0; i < 4; ++i)
#pragma unroll
    for (int j = 0; j < 4; ++j) acc[i][j] = (f32x4)(0.f);
  int lane = threadIdx.x & 63, wave = threadIdx.x >> 6;
  int wm = wave & 1, wn = wave >> 1, col = lane & 15, quad = lane >> 4;

  if (L < 1936) {
    int l = L, g1 = 0;
    if (l >= 968) { g1 = 1; l -= 968; }
    int rowSub = l & 7, t = l >> 3;
    int colIdx = t % 11, rowGroup = t / 11;
    int row0 = (rowGroup * 8 + rowSub) << 7;
    int col0 = colIdx << 7;
    const unsigned short* Am = g1 ? QVb : QKb;
    const unsigned short* Bm = g1 ? SVb : SKb;
    mfma_core((const short*)Am + (size_t)row0 * OUT_DIM, OUT_DIM, min(127, QROWS - 1 - row0),
              (const short*)Bm + (size_t)col0 * OUT_DIM, OUT_DIM, min(127, SROWS - 1 - col0),
              OUT_DIM, lds, acc);
    const float scale = 0.029462782549439483f;  // 1/sqrt(1152)
#pragma unroll
    for (int i = 0; i < 4; ++i)
#pragma unroll
      for (int r = 0; r < 4; ++r) {
        int gr = row0 + wm * 64 + i * 16 + quad * 4 + r;
        if (gr >= QROWS) continue;
#pragma unroll
        for (int j = 0; j < 4; ++j) {
          int gc = col0 + wn * 64 + j * 16 + col;
          if (gc < SROWS) {
            if (g1) {
              int c = gc / 280;
              G1b[(size_t)gr * AT_STRIDE + gc + c * 8] = f2bf(acc[i][j][r]);
            } else {
              SC[(size_t)gr * SC_STRIDE + gc] = acc[i][j][r] * scale;
            }
          }
        }
      }
  } else {
    int l = L - 1936;                 // 0..44
    int c = l / 9, rem = l % 9;
    int i0 = (rem / 3) << 7, j0 = (rem % 3) << 7;
    const short* base = (const short*)SVb + (size_t)c * 280 * OUT_DIM;
    mfma_core(base + (size_t)i0 * OUT_DIM, OUT_DIM, min(127, 279 - i0),
              base + (size_t)j0 * OUT_DIM, OUT_DIM, min(127, 279 - j0),
              OUT_DIM, lds, acc);
    unsigned short* g2c = G2 + (size_t)c * KC * KC;
#pragma unroll
    for (int i = 0; i < 4; ++i)
#pragma unroll
      for (int r = 0; r < 4; ++r) {
        int gi = i0 + wm * 64 + i * 16 + quad * 4 + r;
        if (gi >= KC) continue;
#pragma unroll
        for (int j = 0; j < 4; ++j) {
          int gj = j0 + wn * 64 + j * 16 + col;
          if (gj < KC) g2c[(size_t)gi * KC + gj] = f2bf(acc[i][j][r]);
        }
      }
  }
}

// ---------------- per-class softmax + fused term2 = <attn, g1> ----------------
__global__ __launch_bounds__(256) void k_softmax(const float* __restrict__ SC,
                                                 const unsigned short* __restrict__ G1b,
                                                 unsigned short* __restrict__ ATb,
                                                 float* __restrict__ T2) {
  int row = blockIdx.x, tid = threadIdx.x;
  const float* p = SC + (size_t)row * SC_STRIDE;
  const unsigned short* g1r = G1b + (size_t)row * AT_STRIDE;
  __shared__ float redm[WAY][4];
  __shared__ float reds[WAY][4];
  __shared__ float redt[WAY][4];
  float v[6], gv[6];
  int cls[6], loc[6];
  float m[WAY];
#pragma unroll
  for (int c = 0; c < WAY; ++c) m[c] = -INFINITY;
#pragma unroll
  for (int it = 0; it < 6; ++it) {
    int colx = it * 256 + tid;
    if (colx < SROWS) {
      v[it] = p[colx];
      int c = colx / 280;
      cls[it] = c; loc[it] = colx - c * 280;
      gv[it] = bf2f(g1r[c * KC + loc[it]]);
      m[c] = fmaxf(m[c], v[it]);
    } else cls[it] = -1;
  }
#pragma unroll
  for (int off = 32; off; off >>= 1)
#pragma unroll
    for (int c = 0; c < WAY; ++c) m[c] = fmaxf(m[c], __shfl_xor(m[c], off));
  int wavei = tid >> 6, lane = tid & 63;
  if (lane == 0)
#pragma unroll
    for (int c = 0; c < WAY; ++c) redm[c][wavei] = m[c];
  __syncthreads();
  float M[WAY];
#pragma unroll
  for (int c = 0; c < WAY; ++c)
    M[c] = fmaxf(fmaxf(redm[c][0], redm[c][1]), fmaxf(redm[c][2], redm[c][3]));
  float s[WAY], t2[WAY];
#pragma unroll
  for (int c = 0; c < WAY; ++c) { s[c] = 0.f; t2[c] = 0.f; }
#pragma unroll
  for (int it = 0; it < 6; ++it)
    if (cls[it] >= 0) {
      v[it] = expf(v[it] - M[cls[it]]);
      s[cls[it]] += v[it];
      t2[cls[it]] += v[it] * gv[it];
    }
#pragma unroll
  for (int off = 32; off; off >>= 1)
#pragma unroll
    for (int c = 0; c < WAY; ++c) {
      s[c] += __shfl_xor(s[c], off);
      t2[c] += __shfl_xor(t2[c], off);
    }
  if (lane == 0)
#pragma unroll
    for (int c = 0; c < WAY; ++c) { reds[c][wavei] = s[c]; redt[c][wavei] = t2[c]; }
  __syncthreads();
  float S[WAY];
#pragma unroll
  for (int c = 0; c < WAY; ++c) S[c] = reds[c][0] + reds[c][1] + reds[c][2] + reds[c][3];
  unsigned short* op = ATb + (size_t)row * AT_STRIDE;
#pragma unroll
  for (int it = 0; it < 6; ++it)
    if (cls[it] >= 0) op[cls[it] * KC + loc[it]] = f2bf(v[it] / S[cls[it]]);
  if (tid < WAY * 8) op[(tid >> 3) * KC + 280 + (tid & 7)] = 0;  // zero pads
  if (tid < WAY) {
    float tt = redt[tid][0] + redt[tid][1] + redt[tid][2] + redt[tid][3];
    T2[(size_t)tid * QROWS + row] = tt / S[tid];
  }
}

// ---------------- B2 = attn_c @ G2_c with fused T3 rowdot: T3 = a^T G2 a ----------------
__global__ __launch_bounds__(256) void k_b2t3(const unsigned short* __restrict__ ATb,
                                              const unsigned short* __restrict__ G2,
                                              float* __restrict__ T3) {
  __shared__ short lds[8192];
  __shared__ float rowsum[128];
  int c = blockIdx.z;
  int row0 = blockIdx.y * 128, j0 = blockIdx.x * 128;
  int tid = threadIdx.x;
  if (tid < 128) rowsum[tid] = 0.f;
  f32x4 acc[4][4];
#pragma unroll
  for (int i = 0; i < 4; ++i)
#pragma unroll
    for (int j = 0; j < 4; ++j) acc[i][j] = (f32x4)(0.f);
  mfma_core((const short*)ATb + (size_t)row0 * AT_STRIDE + c * KC, AT_STRIDE,
            min(127, QROWS - 1 - row0),
            (const short*)G2 + (size_t)c * KC * KC + (size_t)j0 * KC, KC,
            min(127, KC - 1 - j0),
            KC, lds, acc);
  int lane = tid & 63, wave = tid >> 6;
  int wm = wave & 1, wn = wave >> 1, quad = lane >> 4, col = lane & 15;
#pragma unroll
  for (int i = 0; i < 4; ++i)
#pragma unroll
    for (int r = 0; r < 4; ++r) {
      int rl = wm * 64 + i * 16 + quad * 4 + r;
      int gr = row0 + rl;
      float sacc = 0.f;
      if (gr < QROWS) {
        const unsigned short* ar = ATb + (size_t)gr * AT_STRIDE + c * KC;
#pragma unroll
        for (int j = 0; j < 4; ++j) {
          int gj = j0 + wn * 64 + j * 16 + col;
          if (gj < KC) sacc += bf2f(ar[gj]) * acc[i][j][r];
        }
      }
#pragma unroll
      for (int mm = 1; mm < 16; mm <<= 1) sacc += __shfl_xor(sacc, mm);
      if (col == 0) atomicAdd(&rowsum[rl], sacc);
    }
  __syncthreads();
  if (tid < 128) {
    int gr = row0 + tid;
    if (gr < QROWS) atomicAdd(&T3[(size_t)c * QROWS + gr], rowsum[tid]);
  }
}

// ---------------- finalize: out[q][c] = -(sum_t qnorm - 2*T2 + T3)/56 ----------------
__global__ __launch_bounds__(64) void k_final(const float* __restrict__ qnorm,
                                              const float* __restrict__ T2,
                                              const float* __restrict__ T3,
                                              float* __restrict__ out) {
  int bid = blockIdx.x;          // 0..999
  int q = bid / WAY, c = bid % WAY;
  int t = threadIdx.x;
  float p = 0.f;
  if (t < NTUP) {
    int r = q * NTUP + t;
    p = qnorm[r] - 2.f * T2[(size_t)c * QROWS + r] + T3[(size_t)c * QROWS + r];
  }
#pragma unroll
  for (int off = 32; off; off >>= 1) p += __shfl_down(p, off);
  if (t == 0) out[q * WAY + c] = -p * (1.f / NTUP);
}

// ---------------- launch ----------------
extern "C" void kernel_launch(void* const* d_in, const int* in_sizes, int n_in,
                              void* d_out, int out_size, void* d_ws, size_t ws_size,
                              hipStream_t stream) {
  const float* support = (const float*)d_in[0];
  const int* labels = (const int*)d_in[1];
  const float* queries = (const float*)d_in[2];
  const float* Wk = (const float*)d_in[3];
  const float* bk = (const float*)d_in[4];
  const float* Wv = (const float*)d_in[5];
  const float* bv = (const float*)d_in[6];
  const float* ln_g = (const float*)d_in[7];
  const float* ln_b = (const float*)d_in[8];
  float* out = (float*)d_out;
  char* w8 = (char*)d_ws;

  float* PE = (float*)(w8 + PE_OFF);
  unsigned short* APb = (unsigned short*)(w8 + APB_OFF);
  unsigned short* WT = (unsigned short*)(w8 + WT_OFF);
  unsigned short* Pb = (unsigned short*)(w8 + PB_OFF);
  unsigned short* QKb = (unsigned short*)(w8 + QKB_OFF);
  unsigned short* SKb = (unsigned short*)(w8 + SKB_OFF);
  unsigned short* QVb = (unsigned short*)(w8 + QVB_OFF);
  unsigned short* SVb = (unsigned short*)(w8 + SVB_OFF);
  unsigned short* G2 = (unsigned short*)(w8 + G2_OFF);
  float* SC = (float*)(w8 + SC_OFF);
  unsigned short* G1b = (unsigned short*)(w8 + G1B_OFF);
  unsigned short* ATb = (unsigned short*)(w8 + ATB_OFF);
  float* QNORM = (float*)(w8 + QNORM_OFF);
  float* T2 = (float*)(w8 + T2_OFF);
  float* T3 = (float*)(w8 + T3_OFF);
  int* RANK = (int*)(w8 + RANK_OFF);

  k_init<<<dim3(227), dim3(256), 0, stream>>>(PE, labels, RANK, T3);
  k_add_pe<<<dim3(1800), dim3(256), 0, stream>>>(support, queries, PE, APb);
  k_wt<<<dim3(64, 36, 6), dim3(32, 8), 0, stream>>>(Wk, Wv, WT);
  k_gemm1<<<dim3(54, 15), dim3(256), 0, stream>>>(APb, WT, Pb);
  k_combine<<<dim3(12600, 2), dim3(192), 0, stream>>>(Pb, bk, bv, ln_g, ln_b, RANK,
                                                      SKb, QKb, SVb, QVb, QNORM);
  k_rowgemm<<<dim3(1981), dim3(256), 0, stream>>>(QKb, SKb, QVb, SVb, SC, G1b, G2);
  k_softmax<<<dim3(11200), dim3(256), 0, stream>>>(SC, G1b, ATb, T2);
  k_b2t3<<<dim3(3, 88, 5), dim3(256), 0, stream>>>(ATb, G2, T3);
  k_final<<<dim3(1000), dim3(64), 0, stream>>>(QNORM, T2, T3, out);
}

// Round 6
// 450.506 us; speedup vs baseline: 5.5100x; 1.0517x over previous
//
#include <hip/hip_runtime.h>
#include <math.h>

// ---------------- problem constants ----------------
#define SEQ_LEN 8
#define IN_DIM 2048
#define OUT_DIM 1152
#define NTUP 56
#define NSUP 25
#define NQ 200
#define WAY 5
#define SFRAMES 200
#define NFRAMES 1800
#define SROWS 1400
#define QROWS 11200
#define AT_STRIDE 1440   // bf16 scores/attn/G1 row stride: 5 classes * 288
#define KC 288           // per-class padded K (280 valid + 8 zeros)

typedef __attribute__((ext_vector_type(8))) short short8;
typedef __attribute__((ext_vector_type(4))) float f32x4;

__device__ __constant__ int TUP[NTUP][3] = {
{0,1,2},{0,1,3},{0,1,4},{0,1,5},{0,1,6},{0,1,7},
{0,2,3},{0,2,4},{0,2,5},{0,2,6},{0,2,7},
{0,3,4},{0,3,5},{0,3,6},{0,3,7},
{0,4,5},{0,4,6},{0,4,7},
{0,5,6},{0,5,7},
{0,6,7},
{1,2,3},{1,2,4},{1,2,5},{1,2,6},{1,2,7},
{1,3,4},{1,3,5},{1,3,6},{1,3,7},
{1,4,5},{1,4,6},{1,4,7},
{1,5,6},{1,5,7},
{1,6,7},
{2,3,4},{2,3,5},{2,3,6},{2,3,7},
{2,4,5},{2,4,6},{2,4,7},
{2,5,6},{2,5,7},
{2,6,7},
{3,4,5},{3,4,6},{3,4,7},
{3,5,6},{3,5,7},
{3,6,7},
{4,5,6},{4,5,7},
{4,6,7},
{5,6,7}};

// ---------------- bf16 helpers ----------------
__device__ __forceinline__ unsigned short f2bf(float x) {
  union { float f; unsigned int u; } v; v.f = x;
  unsigned int r = v.u + 0x7fffu + ((v.u >> 16) & 1u);
  return (unsigned short)(r >> 16);
}
__device__ __forceinline__ float bf2f(unsigned short s) {
  union { float f; unsigned int u; } v; v.u = ((unsigned int)s) << 16;
  return v.f;
}

// async 16B global -> LDS
__device__ __forceinline__ void gll16(const void* g, void* l) {
  __builtin_amdgcn_global_load_lds(
      (const __attribute__((address_space(1))) unsigned int*)g,
      (__attribute__((address_space(3))) unsigned int*)l, 16, 0, 0);
}

// ---------------- workspace byte offsets ----------------
#define APB_OFF   0UL                     // bf16 [1800][2048]    7372800
#define WT_OFF    7372800UL               // bf16 [6912][2048]    28311552
#define PB_OFF    35684352UL              // bf16 [1800][6912]    24883200
#define QKB_OFF   60567552UL              // bf16 [11200][1152]   25804800
#define SKB_OFF   86372352UL              // bf16 [1400][1152]    3225600
#define QVB_OFF   89597952UL              // bf16 [11200][1152]   25804800
#define SVB_OFF   115402752UL             // bf16 [1400][1152]    3225600
#define G2_OFF    118628352UL             // bf16 [5][288][288]   829440
#define SCB_OFF   119457792UL             // bf16 [11200][1440]   32256000
#define G1B_OFF   151713792UL             // bf16 [11200][1440]   32256000
#define ATB_OFF   183969792UL             // bf16 [11200][1440]   32256000
#define QNORM_OFF 216225792UL             // f32  [11200]         44800
#define T2_OFF    216270592UL             // f32  [5][11200]      224000
#define T3_OFF    216494592UL             // f32  [5][11200]      224000
#define RANK_OFF  216718592UL             // i32  [25]

// ---------------- k_pre: fused (X+PE)->bf16, weight transpose, class rank ----------------
// blocks [0,1800): add_pe for frame b (PE computed inline)
// blocks [1800,15624): weight transpose tiles
// block 15624: label rank
__global__ __launch_bounds__(256) void k_pre(const float* __restrict__ S,
                                             const float* __restrict__ Q,
                                             const float* __restrict__ Wk,
                                             const float* __restrict__ Wv,
                                             const int* __restrict__ labels,
                                             unsigned short* __restrict__ APb,
                                             unsigned short* __restrict__ WT,
                                             int* __restrict__ rank) {
  __shared__ float t[32][33];
  int b = blockIdx.x, tid = threadIdx.x;
  if (b < NFRAMES) {
    int frame = b;
    int e8 = tid * 8;
    int pos = frame & 7;
    const float c0 = -logf(10000.0f) / (float)IN_DIM;
    float pe[8];
#pragma unroll
    for (int p = 0; p < 4; ++p) {
      float dt = expf((float)(e8 + 2 * p) * c0);
      float arg = (float)pos * dt;
      pe[2 * p] = sinf(arg) * 0.1f;
      pe[2 * p + 1] = cosf(arg) * 0.1f;
    }
    const float* src = (frame < SFRAMES) ? (S + (size_t)frame * IN_DIM + e8)
                                         : (Q + (size_t)(frame - SFRAMES) * IN_DIM + e8);
    float4 x0 = ((const float4*)src)[0], x1 = ((const float4*)src)[1];
    short8 o;
    o[0] = (short)f2bf(x0.x + pe[0]); o[1] = (short)f2bf(x0.y + pe[1]);
    o[2] = (short)f2bf(x0.z + pe[2]); o[3] = (short)f2bf(x0.w + pe[3]);
    o[4] = (short)f2bf(x1.x + pe[4]); o[5] = (short)f2bf(x1.y + pe[5]);
    o[6] = (short)f2bf(x1.z + pe[6]); o[7] = (short)f2bf(x1.w + pe[7]);
    *(short8*)(APb + (size_t)frame * IN_DIM + e8) = o;
  } else if (b < NFRAMES + 13824) {
    int z = b - NFRAMES;                  // 64 k-tiles x 36 d-tiles x 6 (w,j)
    int bz = z / (64 * 36); int rem = z % (64 * 36);
    int by = rem / 64, bx = rem % 64;
    int w = bz / 3, j = bz % 3;
    const float* W = w ? Wv : Wk;
    int k0 = bx * 32, d0 = by * 32;
    int tx = tid & 31, ty = tid >> 5;
#pragma unroll
    for (int i = 0; i < 4; ++i) {
      int k = k0 + ty + i * 8;
      t[ty + i * 8][tx] = W[(size_t)(j * IN_DIM + k) * OUT_DIM + d0 + tx];
    }
    __syncthreads();
    int colbase = w * 3456 + j * 1152 + d0;
#pragma unroll
    for (int i = 0; i < 4; ++i) {
      int d = ty + i * 8;
      WT[(size_t)(colbase + d) * IN_DIM + k0 + tx] = f2bf(t[tx][d]);
    }
  } else {
    if (tid == 0) {
      for (int s = 0; s < NSUP; ++s) {
        int r = 0;
        for (int s2 = 0; s2 < NSUP; ++s2)
          r += (labels[s2] < labels[s]) || (labels[s2] == labels[s] && s2 < s);
        rank[s] = r;
      }
    }
  }
}

// ---------------- MFMA GEMM core (m97 structure) ----------------
__device__ __forceinline__ void mfma_core(const short* __restrict__ A, int lda, int maxA,
                                          const short* __restrict__ B, int ldb, int maxB,
                                          int K, short* lds, f32x4 (&acc)[4][4]) {
  int tid = threadIdx.x;
  int lane = tid & 63, wave = tid >> 6;
  int wm = wave & 1, wn = wave >> 1;
  int col = lane & 15, quad = lane >> 4;
  short* As = lds;           // [128][32]
  short* Bs = lds + 4096;    // [128][32]
  int s0 = tid, s1 = tid + 256;
  int r0 = s0 >> 2, r1 = s1 >> 2;
  int o0 = (s0 & 3) * 8, o1 = (s1 & 3) * 8;
  const short* a0p = A + (size_t)min(r0, maxA) * lda + o0;
  const short* a1p = A + (size_t)min(r1, maxA) * lda + o1;
  const short* b0p = B + (size_t)min(r0, maxB) * ldb + o0;
  const short* b1p = B + (size_t)min(r1, maxB) * ldb + o1;
  short* la0 = As + s0 * 8; short* la1 = As + s1 * 8;
  short* lb0 = Bs + s0 * 8; short* lb1 = Bs + s1 * 8;

  for (int k0 = 0; k0 < K; k0 += 32) {
    gll16(a0p + k0, la0);
    gll16(a1p + k0, la1);
    gll16(b0p + k0, lb0);
    gll16(b1p + k0, lb1);
    __syncthreads();
    short8 af[4], bf[4];
#pragma unroll
    for (int i = 0; i < 4; ++i)
      af[i] = *(const short8*)(As + (wm * 64 + i * 16 + col) * 32 + quad * 8);
#pragma unroll
    for (int j = 0; j < 4; ++j)
      bf[j] = *(const short8*)(Bs + (wn * 64 + j * 16 + col) * 32 + quad * 8);
#pragma unroll
    for (int i = 0; i < 4; ++i)
#pragma unroll
      for (int j = 0; j < 4; ++j)
        acc[i][j] = __builtin_amdgcn_mfma_f32_16x16x32_bf16(af[i], bf[j], acc[i][j], 0, 0, 0);
    __syncthreads();
  }
}

// ---------------- GEMM1: Pb[1800][6912] = APb @ WT^T ----------------
__global__ __launch_bounds__(256) void k_gemm1(const unsigned short* __restrict__ APb,
                                               const unsigned short* __restrict__ WT,
                                               unsigned short* __restrict__ Pb) {
  __shared__ short lds[8192];
  int row0 = blockIdx.y * 128, col0 = blockIdx.x * 128;
  f32x4 acc[4][4];
#pragma unroll
  for (int i = 0; i < 4; ++i)
#pragma unroll
    for (int j = 0; j < 4; ++j) acc[i][j] = (f32x4)(0.f);
  mfma_core((const short*)APb + (size_t)row0 * IN_DIM, IN_DIM, min(127, NFRAMES - 1 - row0),
            (const short*)WT + (size_t)col0 * IN_DIM, IN_DIM, 127,
            IN_DIM, lds, acc);
  int lane = threadIdx.x & 63, wave = threadIdx.x >> 6;
  int wm = wave & 1, wn = wave >> 1, col = lane & 15, quad = lane >> 4;
#pragma unroll
  for (int i = 0; i < 4; ++i)
#pragma unroll
    for (int r = 0; r < 4; ++r) {
      int gr = row0 + wm * 64 + i * 16 + quad * 4 + r;
      if (gr >= NFRAMES) continue;
#pragma unroll
      for (int j = 0; j < 4; ++j)
        Pb[(size_t)gr * 6912 + col0 + wn * 64 + j * 16 + col] = f2bf(acc[i][j][r]);
    }
}

// ---------------- combine: sum 3 frame projections, +bias, LN(k), qnorm(v) ----------------
// packed 2xbf16 (uint) loads/stores
__global__ __launch_bounds__(192) void k_combine(const unsigned short* __restrict__ Pb,
                                                 const float* __restrict__ bk,
                                                 const float* __restrict__ bv,
                                                 const float* __restrict__ g,
                                                 const float* __restrict__ bb,
                                                 const int* __restrict__ rank,
                                                 unsigned short* __restrict__ SKb,
                                                 unsigned short* __restrict__ QKb,
                                                 unsigned short* __restrict__ SVb,
                                                 unsigned short* __restrict__ QVb,
                                                 float* __restrict__ qnorm) {
  __shared__ float s1[3], s2[3];
  int row = blockIdx.x;     // 0..12599
  int w = blockIdx.y;       // 0 = k, 1 = v
  int tid = threadIdx.x;
  bool isq = row >= SROWS;
  int r = isq ? row - SROWS : row;
  int n = r / NTUP, t = r - n * NTUP;
  int orow = isq ? r : (rank[n] * NTUP + t);
  int fbase = (isq ? SFRAMES + n * SEQ_LEN : n * SEQ_LEN);
  const unsigned short* p0 = Pb + (size_t)(fbase + TUP[t][0]) * 6912 + w * 3456;
  const unsigned short* p1 = Pb + (size_t)(fbase + TUP[t][1]) * 6912 + w * 3456 + 1152;
  const unsigned short* p2 = Pb + (size_t)(fbase + TUP[t][2]) * 6912 + w * 3456 + 2304;
  const float* bias = w ? bv : bk;
  float v[6];
  float sum = 0.f, sq = 0.f;
#pragma unroll
  for (int i = 0; i < 3; ++i) {
    int d2 = tid + i * 192;                 // pair index
    unsigned int u0 = *(const unsigned int*)(p0 + 2 * d2);
    unsigned int u1 = *(const unsigned int*)(p1 + 2 * d2);
    unsigned int u2 = *(const unsigned int*)(p2 + 2 * d2);
    float2 bi = *(const float2*)(bias + 2 * d2);
    float a = bf2f((unsigned short)u0) + bf2f((unsigned short)u1) + bf2f((unsigned short)u2) + bi.x;
    float b = bf2f((unsigned short)(u0 >> 16)) + bf2f((unsigned short)(u1 >> 16)) +
              bf2f((unsigned short)(u2 >> 16)) + bi.y;
    v[2 * i] = a; v[2 * i + 1] = b;
    sum += a + b;
    sq += a * a + b * b;
  }
  int wavei = tid >> 6, lane = tid & 63;
  if (w == 0) {
#pragma unroll
    for (int off = 32; off; off >>= 1) {
      sum += __shfl_down(sum, off);
      sq += __shfl_down(sq, off);
    }
    if (lane == 0) { s1[wavei] = sum; s2[wavei] = sq; }
    __syncthreads();
    float tot = s1[0] + s1[1] + s1[2];
    float tot2 = s2[0] + s2[1] + s2[2];
    float mean = tot * (1.f / OUT_DIM);
    float var = tot2 * (1.f / OUT_DIM) - mean * mean;
    float inv = rsqrtf(var + 1e-5f);
    unsigned short* outp = isq ? (QKb + (size_t)orow * OUT_DIM) : (SKb + (size_t)orow * OUT_DIM);
#pragma unroll
    for (int i = 0; i < 3; ++i) {
      int d2 = tid + i * 192;
      float2 gg = *(const float2*)(g + 2 * d2);
      float2 bbv = *(const float2*)(bb + 2 * d2);
      unsigned int lo = f2bf((v[2 * i] - mean) * inv * gg.x + bbv.x);
      unsigned int hi = f2bf((v[2 * i + 1] - mean) * inv * gg.y + bbv.y);
      *(unsigned int*)(outp + 2 * d2) = lo | (hi << 16);
    }
  } else {
    unsigned short* outp = isq ? (QVb + (size_t)orow * OUT_DIM) : (SVb + (size_t)orow * OUT_DIM);
#pragma unroll
    for (int i = 0; i < 3; ++i) {
      int d2 = tid + i * 192;
      unsigned int lo = f2bf(v[2 * i]);
      unsigned int hi = f2bf(v[2 * i + 1]);
      *(unsigned int*)(outp + 2 * d2) = lo | (hi << 16);
    }
    if (isq) {
#pragma unroll
      for (int off = 32; off; off >>= 1) sq += __shfl_down(sq, off);
      if (lane == 0) s2[wavei] = sq;
      __syncthreads();
      if (tid == 0) qnorm[orow] = s2[0] + s2[1] + s2[2];
    }
  }
}

// ---------------- merged: scores / G1 (XCD-swizzled, bf16 class-padded out) + Gram G2 tail ----------------
__global__ __launch_bounds__(256) void k_rowgemm(const unsigned short* __restrict__ QKb,
                                                 const unsigned short* __restrict__ SKb,
                                                 const unsigned short* __restrict__ QVb,
                                                 const unsigned short* __restrict__ SVb,
                                                 unsigned short* __restrict__ SCb,
                                                 unsigned short* __restrict__ G1b,
                                                 unsigned short* __restrict__ G2) {
  __shared__ short lds[8192];
  int L = blockIdx.x;
  f32x4 acc[4][4];
#pragma unroll
  for (int i = 0; i < 4; ++i)
#pragma unroll
    for (int j = 0; j < 4; ++j) acc[i][j] = (f32x4)(0.f);
  int lane = threadIdx.x & 63, wave = threadIdx.x >> 6;
  int wm = wave & 1, wn = wave >> 1, col = lane & 15, quad = lane >> 4;

  if (L < 1936) {
    int l = L, g1 = 0;
    if (l >= 968) { g1 = 1; l -= 968; }
    int rowSub = l & 7, t = l >> 3;
    int colIdx = t % 11, rowGroup = t / 11;
    int row0 = (rowGroup * 8 + rowSub) << 7;
    int col0 = colIdx << 7;
    const unsigned short* Am = g1 ? QVb : QKb;
    const unsigned short* Bm = g1 ? SVb : SKb;
    mfma_core((const short*)Am + (size_t)row0 * OUT_DIM, OUT_DIM, min(127, QROWS - 1 - row0),
              (const short*)Bm + (size_t)col0 * OUT_DIM, OUT_DIM, min(127, SROWS - 1 - col0),
              OUT_DIM, lds, acc);
    unsigned short* outp = g1 ? G1b : SCb;
    const float scl = g1 ? 1.0f : 0.029462782549439483f;  // 1/sqrt(1152)
#pragma unroll
    for (int i = 0; i < 4; ++i)
#pragma unroll
      for (int r = 0; r < 4; ++r) {
        int gr = row0 + wm * 64 + i * 16 + quad * 4 + r;
        if (gr >= QROWS) continue;
#pragma unroll
        for (int j = 0; j < 4; ++j) {
          int gc = col0 + wn * 64 + j * 16 + col;
          if (gc < SROWS) {
            int c = gc / 280;
            outp[(size_t)gr * AT_STRIDE + gc + c * 8] = f2bf(acc[i][j][r] * scl);
          }
        }
      }
  } else {
    int l = L - 1936;                 // 0..44: G2[c] = SV_c @ SV_c^T
    int c = l / 9, rem = l % 9;
    int i0 = (rem / 3) << 7, j0 = (rem % 3) << 7;
    const short* base = (const short*)SVb + (size_t)c * 280 * OUT_DIM;
    mfma_core(base + (size_t)i0 * OUT_DIM, OUT_DIM, min(127, 279 - i0),
              base + (size_t)j0 * OUT_DIM, OUT_DIM, min(127, 279 - j0),
              OUT_DIM, lds, acc);
    unsigned short* g2c = G2 + (size_t)c * KC * KC;
#pragma unroll
    for (int i = 0; i < 4; ++i)
#pragma unroll
      for (int r = 0; r < 4; ++r) {
        int gi = i0 + wm * 64 + i * 16 + quad * 4 + r;
        if (gi >= KC) continue;
#pragma unroll
        for (int j = 0; j < 4; ++j) {
          int gj = j0 + wn * 64 + j * 16 + col;
          if (gj < KC) g2c[(size_t)gi * KC + gj] = f2bf(acc[i][j][r]);
        }
      }
  }
}

// ---------------- per-class softmax + fused term2, vectorized (ushort8 per thread) ----------------
// 280 = 35*8, so 8-wide groups never straddle class boundaries.
__global__ __launch_bounds__(256) void k_softmax(const unsigned short* __restrict__ SCb,
                                                 const unsigned short* __restrict__ G1b,
                                                 unsigned short* __restrict__ ATb,
                                                 float* __restrict__ T2) {
  int row = blockIdx.x, tid = threadIdx.x;
  const unsigned short* ps = SCb + (size_t)row * AT_STRIDE;
  const unsigned short* pg = G1b + (size_t)row * AT_STRIDE;
  __shared__ float redm[WAY][4];
  __shared__ float reds[WAY][4];
  __shared__ float redt[WAY][4];
  float v[8], gv[8];
  int myc = -1, off = 0;
  if (tid < 175) {
    myc = tid / 35;
    off = myc * KC + (tid - myc * 35) * 8;
    short8 sv8 = *(const short8*)(ps + off);
    short8 gv8 = *(const short8*)(pg + off);
#pragma unroll
    for (int i = 0; i < 8; ++i) {
      v[i] = bf2f((unsigned short)sv8[i]);
      gv[i] = bf2f((unsigned short)gv8[i]);
    }
  }
  float m[WAY];
#pragma unroll
  for (int c = 0; c < WAY; ++c) m[c] = -INFINITY;
  if (myc >= 0)
#pragma unroll
    for (int i = 0; i < 8; ++i) m[myc] = fmaxf(m[myc], v[i]);
#pragma unroll
  for (int o = 32; o; o >>= 1)
#pragma unroll
    for (int c = 0; c < WAY; ++c) m[c] = fmaxf(m[c], __shfl_xor(m[c], o));
  int wavei = tid >> 6, lane = tid & 63;
  if (lane == 0)
#pragma unroll
    for (int c = 0; c < WAY; ++c) redm[c][wavei] = m[c];
  __syncthreads();
  float M[WAY];
#pragma unroll
  for (int c = 0; c < WAY; ++c)
    M[c] = fmaxf(fmaxf(redm[c][0], redm[c][1]), fmaxf(redm[c][2], redm[c][3]));
  float s[WAY], t2[WAY];
#pragma unroll
  for (int c = 0; c < WAY; ++c) { s[c] = 0.f; t2[c] = 0.f; }
  if (myc >= 0) {
#pragma unroll
    for (int i = 0; i < 8; ++i) {
      v[i] = expf(v[i] - M[myc]);
      s[myc] += v[i];
      t2[myc] += v[i] * gv[i];
    }
  }
#pragma unroll
  for (int o = 32; o; o >>= 1)
#pragma unroll
    for (int c = 0; c < WAY; ++c) {
      s[c] += __shfl_xor(s[c], o);
      t2[c] += __shfl_xor(t2[c], o);
    }
  if (lane == 0)
#pragma unroll
    for (int c = 0; c < WAY; ++c) { reds[c][wavei] = s[c]; redt[c][wavei] = t2[c]; }
  __syncthreads();
  float S[WAY];
#pragma unroll
  for (int c = 0; c < WAY; ++c) S[c] = reds[c][0] + reds[c][1] + reds[c][2] + reds[c][3];
  unsigned short* op = ATb + (size_t)row * AT_STRIDE;
  if (myc >= 0) {
    float inv = 1.f / S[myc];
    short8 o8;
#pragma unroll
    for (int i = 0; i < 8; ++i) o8[i] = (short)f2bf(v[i] * inv);
    *(short8*)(op + off) = o8;
  } else if (tid >= 175 && tid < 180) {   // zero the per-class pads (8 shorts each)
    short8 z = (short8)0;
    *(short8*)(op + (tid - 175) * KC + 280) = z;
  }
  if (tid < WAY) {
    float tt = redt[tid][0] + redt[tid][1] + redt[tid][2] + redt[tid][3];
    T2[(size_t)tid * QROWS + row] = tt / S[tid];
  }
}

// ---------------- T3 = a^T G2 a, one block per (row-tile, class), j0-tiles looped ----------------
__global__ __launch_bounds__(256) void k_b2t3(const unsigned short* __restrict__ ATb,
                                              const unsigned short* __restrict__ G2,
                                              float* __restrict__ T3) {
  __shared__ short lds[8192];
  __shared__ float rowsum[128];
  int c = blockIdx.y;
  int row0 = blockIdx.x * 128;
  int tid = threadIdx.x;
  if (tid < 128) rowsum[tid] = 0.f;
  int lane = tid & 63, wave = tid >> 6;
  int wm = wave & 1, wn = wave >> 1, quad = lane >> 4, col = lane & 15;
  const short* Abase = (const short*)ATb + (size_t)row0 * AT_STRIDE + c * KC;
  int maxA = min(127, QROWS - 1 - row0);
  float part[4][4] = {};
  for (int j0 = 0; j0 < KC; j0 += 128) {
    f32x4 acc[4][4];
#pragma unroll
    for (int i = 0; i < 4; ++i)
#pragma unroll
      for (int j = 0; j < 4; ++j) acc[i][j] = (f32x4)(0.f);
    mfma_core(Abase, AT_STRIDE, maxA,
              (const short*)G2 + (size_t)c * KC * KC + (size_t)j0 * KC, KC,
              min(127, KC - 1 - j0), KC, lds, acc);
#pragma unroll
    for (int i = 0; i < 4; ++i)
#pragma unroll
      for (int r = 0; r < 4; ++r) {
        int gr = row0 + wm * 64 + i * 16 + quad * 4 + r;
        if (gr < QROWS) {
          const unsigned short* ar = ATb + (size_t)gr * AT_STRIDE + c * KC;
#pragma unroll
          for (int j = 0; j < 4; ++j) {
            int gj = j0 + wn * 64 + j * 16 + col;
            if (gj < KC) part[i][r] += bf2f(ar[gj]) * acc[i][j][r];
          }
        }
      }
  }
#pragma unroll
  for (int i = 0; i < 4; ++i)
#pragma unroll
    for (int r = 0; r < 4; ++r) {
      float sacc = part[i][r];
#pragma unroll
      for (int mm = 1; mm < 16; mm <<= 1) sacc += __shfl_xor(sacc, mm);
      if (col == 0) atomicAdd(&rowsum[wm * 64 + i * 16 + quad * 4 + r], sacc);
    }
  __syncthreads();
  if (tid < 128) {
    int gr = row0 + tid;
    if (gr < QROWS) T3[(size_t)c * QROWS + gr] = rowsum[tid];   // sole owner: plain store
  }
}

// ---------------- finalize: out[q][c] = -(sum_t qnorm - 2*T2 + T3)/56 ----------------
__global__ __launch_bounds__(64) void k_final(const float* __restrict__ qnorm,
                                              const float* __restrict__ T2,
                                              const float* __restrict__ T3,
                                              float* __restrict__ out) {
  int bid = blockIdx.x;          // 0..999
  int q = bid / WAY, c = bid % WAY;
  int t = threadIdx.x;
  float p = 0.f;
  if (t < NTUP) {
    int r = q * NTUP + t;
    p = qnorm[r] - 2.f * T2[(size_t)c * QROWS + r] + T3[(size_t)c * QROWS + r];
  }
#pragma unroll
  for (int off = 32; off; off >>= 1) p += __shfl_down(p, off);
  if (t == 0) out[q * WAY + c] = -p * (1.f / NTUP);
}

// ---------------- launch ----------------
extern "C" void kernel_launch(void* const* d_in, const int* in_sizes, int n_in,
                              void* d_out, int out_size, void* d_ws, size_t ws_size,
                              hipStream_t stream) {
  const float* support = (const float*)d_in[0];
  const int* labels = (const int*)d_in[1];
  const float* queries = (const float*)d_in[2];
  const float* Wk = (const float*)d_in[3];
  const float* bk = (const float*)d_in[4];
  const float* Wv = (const float*)d_in[5];
  const float* bv = (const float*)d_in[6];
  const float* ln_g = (const float*)d_in[7];
  const float* ln_b = (const float*)d_in[8];
  float* out = (float*)d_out;
  char* w8 = (char*)d_ws;

  unsigned short* APb = (unsigned short*)(w8 + APB_OFF);
  unsigned short* WT = (unsigned short*)(w8 + WT_OFF);
  unsigned short* Pb = (unsigned short*)(w8 + PB_OFF);
  unsigned short* QKb = (unsigned short*)(w8 + QKB_OFF);
  unsigned short* SKb = (unsigned short*)(w8 + SKB_OFF);
  unsigned short* QVb = (unsigned short*)(w8 + QVB_OFF);
  unsigned short* SVb = (unsigned short*)(w8 + SVB_OFF);
  unsigned short* G2 = (unsigned short*)(w8 + G2_OFF);
  unsigned short* SCb = (unsigned short*)(w8 + SCB_OFF);
  unsigned short* G1b = (unsigned short*)(w8 + G1B_OFF);
  unsigned short* ATb = (unsigned short*)(w8 + ATB_OFF);
  float* QNORM = (float*)(w8 + QNORM_OFF);
  float* T2 = (float*)(w8 + T2_OFF);
  float* T3 = (float*)(w8 + T3_OFF);
  int* RANK = (int*)(w8 + RANK_OFF);

  k_pre<<<dim3(NFRAMES + 13824 + 1), dim3(256), 0, stream>>>(support, queries, Wk, Wv,
                                                             labels, APb, WT, RANK);
  k_gemm1<<<dim3(54, 15), dim3(256), 0, stream>>>(APb, WT, Pb);
  k_combine<<<dim3(12600, 2), dim3(192), 0, stream>>>(Pb, bk, bv, ln_g, ln_b, RANK,
                                                      SKb, QKb, SVb, QVb, QNORM);
  k_rowgemm<<<dim3(1981), dim3(256), 0, stream>>>(QKb, SKb, QVb, SVb, SCb, G1b, G2);
  k_softmax<<<dim3(11200), dim3(256), 0, stream>>>(SCb, G1b, ATb, T2);
  k_b2t3<<<dim3(88, 5), dim3(256), 0, stream>>>(ATb, G2, T3);
  k_final<<<dim3(1000), dim3(64), 0, stream>>>(QNORM, T2, T3, out);
}

// Round 7
// 399.091 us; speedup vs baseline: 6.2199x; 1.1288x over previous
//
#include <hip/hip_runtime.h>
#include <math.h>

// ---------------- problem constants ----------------
#define SEQ_LEN 8
#define IN_DIM 2048
#define OUT_DIM 1152
#define NTUP 56
#define NSUP 25
#define NQ 200
#define WAY 5
#define SFRAMES 200
#define NFRAMES 1800
#define SROWS 1400
#define QROWS 11200
#define AT_STRIDE 1440   // bf16 scores/G1 row stride: 5 classes * 288
#define KC 288           // per-class padded K (280 valid + 8 zeros)
#define ALD 296          // attn LDS row stride (shorts), padded for bank spread

typedef __attribute__((ext_vector_type(8))) short short8;
typedef __attribute__((ext_vector_type(4))) float f32x4;

__device__ __constant__ int TUP[NTUP][3] = {
{0,1,2},{0,1,3},{0,1,4},{0,1,5},{0,1,6},{0,1,7},
{0,2,3},{0,2,4},{0,2,5},{0,2,6},{0,2,7},
{0,3,4},{0,3,5},{0,3,6},{0,3,7},
{0,4,5},{0,4,6},{0,4,7},
{0,5,6},{0,5,7},
{0,6,7},
{1,2,3},{1,2,4},{1,2,5},{1,2,6},{1,2,7},
{1,3,4},{1,3,5},{1,3,6},{1,3,7},
{1,4,5},{1,4,6},{1,4,7},
{1,5,6},{1,5,7},
{1,6,7},
{2,3,4},{2,3,5},{2,3,6},{2,3,7},
{2,4,5},{2,4,6},{2,4,7},
{2,5,6},{2,5,7},
{2,6,7},
{3,4,5},{3,4,6},{3,4,7},
{3,5,6},{3,5,7},
{3,6,7},
{4,5,6},{4,5,7},
{4,6,7},
{5,6,7}};

// ---------------- bf16 helpers ----------------
__device__ __forceinline__ unsigned short f2bf(float x) {
  union { float f; unsigned int u; } v; v.f = x;
  unsigned int r = v.u + 0x7fffu + ((v.u >> 16) & 1u);
  return (unsigned short)(r >> 16);
}
__device__ __forceinline__ float bf2f(unsigned short s) {
  union { float f; unsigned int u; } v; v.u = ((unsigned int)s) << 16;
  return v.f;
}

// async 16B global -> LDS
__device__ __forceinline__ void gll16(const void* g, void* l) {
  __builtin_amdgcn_global_load_lds(
      (const __attribute__((address_space(1))) unsigned int*)g,
      (__attribute__((address_space(3))) unsigned int*)l, 16, 0, 0);
}

// ---------------- workspace byte offsets ----------------
#define APB_OFF   0UL                     // bf16 [1800][2048]
#define WT_OFF    7372800UL               // bf16 [6912][2048]
#define PB_OFF    35684352UL              // bf16 [1800][6912]
#define QKB_OFF   60567552UL              // bf16 [11200][1152]
#define SKB_OFF   86372352UL              // bf16 [1400][1152] class-sorted
#define QVB_OFF   89597952UL              // bf16 [11200][1152]
#define SVB_OFF   115402752UL             // bf16 [1400][1152] class-sorted
#define G2_OFF    118628352UL             // bf16 [5][288][288] Gram
#define SCB_OFF   119457792UL             // bf16 [11200][1440] class-padded
#define G1B_OFF   151713792UL             // bf16 [11200][1440] class-padded
#define QNORM_OFF 183969792UL             // f32  [11200]
#define RANK_OFF  184014592UL             // i32  [25]

// ---------------- k_pre: fused (X+PE)->bf16, weight transpose, rank, out-zero ----------------
__global__ __launch_bounds__(256) void k_pre(const float* __restrict__ S,
                                             const float* __restrict__ Q,
                                             const float* __restrict__ Wk,
                                             const float* __restrict__ Wv,
                                             const int* __restrict__ labels,
                                             unsigned short* __restrict__ APb,
                                             unsigned short* __restrict__ WT,
                                             int* __restrict__ rank,
                                             float* __restrict__ outz) {
  __shared__ float t[32][33];
  int b = blockIdx.x, tid = threadIdx.x;
  if (b < NFRAMES) {
    int frame = b;
    int e8 = tid * 8;
    int pos = frame & 7;
    const float c0 = -logf(10000.0f) / (float)IN_DIM;
    float pe[8];
#pragma unroll
    for (int p = 0; p < 4; ++p) {
      float dt = expf((float)(e8 + 2 * p) * c0);
      float arg = (float)pos * dt;
      pe[2 * p] = sinf(arg) * 0.1f;
      pe[2 * p + 1] = cosf(arg) * 0.1f;
    }
    const float* src = (frame < SFRAMES) ? (S + (size_t)frame * IN_DIM + e8)
                                         : (Q + (size_t)(frame - SFRAMES) * IN_DIM + e8);
    float4 x0 = ((const float4*)src)[0], x1 = ((const float4*)src)[1];
    short8 o;
    o[0] = (short)f2bf(x0.x + pe[0]); o[1] = (short)f2bf(x0.y + pe[1]);
    o[2] = (short)f2bf(x0.z + pe[2]); o[3] = (short)f2bf(x0.w + pe[3]);
    o[4] = (short)f2bf(x1.x + pe[4]); o[5] = (short)f2bf(x1.y + pe[5]);
    o[6] = (short)f2bf(x1.z + pe[6]); o[7] = (short)f2bf(x1.w + pe[7]);
    *(short8*)(APb + (size_t)frame * IN_DIM + e8) = o;
  } else if (b < NFRAMES + 13824) {
    int z = b - NFRAMES;                  // 64 k-tiles x 36 d-tiles x 6 (w,j)
    int bz = z / (64 * 36); int rem = z % (64 * 36);
    int by = rem / 64, bx = rem % 64;
    int w = bz / 3, j = bz % 3;
    const float* W = w ? Wv : Wk;
    int k0 = bx * 32, d0 = by * 32;
    int tx = tid & 31, ty = tid >> 5;
#pragma unroll
    for (int i = 0; i < 4; ++i) {
      int k = k0 + ty + i * 8;
      t[ty + i * 8][tx] = W[(size_t)(j * IN_DIM + k) * OUT_DIM + d0 + tx];
    }
    __syncthreads();
    int colbase = w * 3456 + j * 1152 + d0;
#pragma unroll
    for (int i = 0; i < 4; ++i) {
      int d = ty + i * 8;
      WT[(size_t)(colbase + d) * IN_DIM + k0 + tx] = f2bf(t[tx][d]);
    }
  } else {
    for (int i = tid; i < NQ * WAY; i += 256) outz[i] = 0.f;
    if (tid == 0) {
      for (int s = 0; s < NSUP; ++s) {
        int r = 0;
        for (int s2 = 0; s2 < NSUP; ++s2)
          r += (labels[s2] < labels[s]) || (labels[s2] == labels[s] && s2 < s);
        rank[s] = r;
      }
    }
  }
}

// ---------------- MFMA GEMM core (m97 structure) ----------------
__device__ __forceinline__ void mfma_core(const short* __restrict__ A, int lda, int maxA,
                                          const short* __restrict__ B, int ldb, int maxB,
                                          int K, short* lds, f32x4 (&acc)[4][4]) {
  int tid = threadIdx.x;
  int lane = tid & 63, wave = tid >> 6;
  int wm = wave & 1, wn = wave >> 1;
  int col = lane & 15, quad = lane >> 4;
  short* As = lds;           // [128][32]
  short* Bs = lds + 4096;    // [128][32]
  int s0 = tid, s1 = tid + 256;
  int r0 = s0 >> 2, r1 = s1 >> 2;
  int o0 = (s0 & 3) * 8, o1 = (s1 & 3) * 8;
  const short* a0p = A + (size_t)min(r0, maxA) * lda + o0;
  const short* a1p = A + (size_t)min(r1, maxA) * lda + o1;
  const short* b0p = B + (size_t)min(r0, maxB) * ldb + o0;
  const short* b1p = B + (size_t)min(r1, maxB) * ldb + o1;
  short* la0 = As + s0 * 8; short* la1 = As + s1 * 8;
  short* lb0 = Bs + s0 * 8; short* lb1 = Bs + s1 * 8;

  for (int k0 = 0; k0 < K; k0 += 32) {
    gll16(a0p + k0, la0);
    gll16(a1p + k0, la1);
    gll16(b0p + k0, lb0);
    gll16(b1p + k0, lb1);
    __syncthreads();
    short8 af[4], bf[4];
#pragma unroll
    for (int i = 0; i < 4; ++i)
      af[i] = *(const short8*)(As + (wm * 64 + i * 16 + col) * 32 + quad * 8);
#pragma unroll
    for (int j = 0; j < 4; ++j)
      bf[j] = *(const short8*)(Bs + (wn * 64 + j * 16 + col) * 32 + quad * 8);
#pragma unroll
    for (int i = 0; i < 4; ++i)
#pragma unroll
      for (int j = 0; j < 4; ++j)
        acc[i][j] = __builtin_amdgcn_mfma_f32_16x16x32_bf16(af[i], bf[j], acc[i][j], 0, 0, 0);
    __syncthreads();
  }
}

// ---------------- GEMM1: Pb[1800][6912] = APb @ WT^T ----------------
__global__ __launch_bounds__(256) void k_gemm1(const unsigned short* __restrict__ APb,
                                               const unsigned short* __restrict__ WT,
                                               unsigned short* __restrict__ Pb) {
  __shared__ short lds[8192];
  int row0 = blockIdx.y * 128, col0 = blockIdx.x * 128;
  f32x4 acc[4][4];
#pragma unroll
  for (int i = 0; i < 4; ++i)
#pragma unroll
    for (int j = 0; j < 4; ++j) acc[i][j] = (f32x4)(0.f);
  mfma_core((const short*)APb + (size_t)row0 * IN_DIM, IN_DIM, min(127, NFRAMES - 1 - row0),
            (const short*)WT + (size_t)col0 * IN_DIM, IN_DIM, 127,
            IN_DIM, lds, acc);
  int lane = threadIdx.x & 63, wave = threadIdx.x >> 6;
  int wm = wave & 1, wn = wave >> 1, col = lane & 15, quad = lane >> 4;
#pragma unroll
  for (int i = 0; i < 4; ++i)
#pragma unroll
    for (int r = 0; r < 4; ++r) {
      int gr = row0 + wm * 64 + i * 16 + quad * 4 + r;
      if (gr >= NFRAMES) continue;
#pragma unroll
      for (int j = 0; j < 4; ++j)
        Pb[(size_t)gr * 6912 + col0 + wn * 64 + j * 16 + col] = f2bf(acc[i][j][r]);
    }
}

// ---------------- combine (clip-LDS): one block per (clip, k/v) ----------------
// Stage the clip's 8 frame-halves (8x3456 bf16 = 55 KB) in LDS once; one wave
// per tuple computes sum + bias (+LN for k) from LDS. Read traffic = Pb once.
__global__ __launch_bounds__(256) void k_combine(const unsigned short* __restrict__ Pb,
                                                 const float* __restrict__ bk,
                                                 const float* __restrict__ bv,
                                                 const float* __restrict__ g,
                                                 const float* __restrict__ bb,
                                                 const int* __restrict__ rank,
                                                 unsigned short* __restrict__ SKb,
                                                 unsigned short* __restrict__ QKb,
                                                 unsigned short* __restrict__ SVb,
                                                 unsigned short* __restrict__ QVb,
                                                 float* __restrict__ qnorm) {
  __shared__ short L[8 * 3456];
  int n = blockIdx.x, w = blockIdx.y;
  int tid = threadIdx.x;
  bool sup = n < NSUP;
  int fbase = sup ? n * SEQ_LEN : SFRAMES + (n - NSUP) * SEQ_LEN;
  for (int i = 0; i < 14; ++i) {
    int idx = tid + 256 * i;          // vec8 index < 3456
    if (idx < 3456) {
      int fr = idx / 432, off = (idx - fr * 432) * 8;
      *(short8*)(L + fr * 3456 + off) =
          *(const short8*)(Pb + (size_t)(fbase + fr) * 6912 + w * 3456 + off);
    }
  }
  __syncthreads();
  int wave = tid >> 6, lane = tid & 63;
  const float* bias = w ? bv : bk;
  float2 bi[9], gg[9], bbv[9];
#pragma unroll
  for (int i = 0; i < 9; ++i) {
    int p = lane + 64 * i;
    bi[i] = *(const float2*)(bias + 2 * p);
    if (w == 0) {
      gg[i] = *(const float2*)(g + 2 * p);
      bbv[i] = *(const float2*)(bb + 2 * p);
    }
  }
  int obase = sup ? rank[n] * NTUP : (n - NSUP) * NTUP;
  const unsigned int* Lu = (const unsigned int*)L;
  for (int t = wave; t < NTUP; t += 4) {
    int b0 = (TUP[t][0] * 3456) >> 1;
    int b1 = (TUP[t][1] * 3456 + 1152) >> 1;
    int b2 = (TUP[t][2] * 3456 + 2304) >> 1;
    float va[18];
    float sum = 0.f, sq = 0.f;
#pragma unroll
    for (int i = 0; i < 9; ++i) {
      int p = lane + 64 * i;
      unsigned int u0 = Lu[b0 + p], u1 = Lu[b1 + p], u2 = Lu[b2 + p];
      float a = bf2f((unsigned short)u0) + bf2f((unsigned short)u1) +
                bf2f((unsigned short)u2) + bi[i].x;
      float b = bf2f((unsigned short)(u0 >> 16)) + bf2f((unsigned short)(u1 >> 16)) +
                bf2f((unsigned short)(u2 >> 16)) + bi[i].y;
      va[2 * i] = a; va[2 * i + 1] = b;
      sum += a + b;
      sq += a * a + b * b;
    }
#pragma unroll
    for (int o = 32; o; o >>= 1) {
      sum += __shfl_xor(sum, o);
      sq += __shfl_xor(sq, o);
    }
    int orow = obase + t;
    if (w == 0) {
      float mean = sum * (1.f / OUT_DIM);
      float var = sq * (1.f / OUT_DIM) - mean * mean;
      float inv = rsqrtf(var + 1e-5f);
      unsigned short* outp = (sup ? SKb : QKb) + (size_t)orow * OUT_DIM;
#pragma unroll
      for (int i = 0; i < 9; ++i) {
        int p = lane + 64 * i;
        unsigned int lo = f2bf((va[2 * i] - mean) * inv * gg[i].x + bbv[i].x);
        unsigned int hi = f2bf((va[2 * i + 1] - mean) * inv * gg[i].y + bbv[i].y);
        *(unsigned int*)(outp + 2 * p) = lo | (hi << 16);
      }
    } else {
      unsigned short* outp = (sup ? SVb : QVb) + (size_t)orow * OUT_DIM;
#pragma unroll
      for (int i = 0; i < 9; ++i) {
        int p = lane + 64 * i;
        unsigned int lo = f2bf(va[2 * i]);
        unsigned int hi = f2bf(va[2 * i + 1]);
        *(unsigned int*)(outp + 2 * p) = lo | (hi << 16);
      }
      if (!sup && lane == 0) qnorm[orow] = sq;
    }
  }
}

// ---------------- merged: scores / G1 (XCD-swizzled, bf16 class-padded out) + Gram G2 tail ----------------
__global__ __launch_bounds__(256) void k_rowgemm(const unsigned short* __restrict__ QKb,
                                                 const unsigned short* __restrict__ SKb,
                                                 const unsigned short* __restrict__ QVb,
                                                 const unsigned short* __restrict__ SVb,
                                                 unsigned short* __restrict__ SCb,
                                                 unsigned short* __restrict__ G1b,
                                                 unsigned short* __restrict__ G2) {
  __shared__ short lds[8192];
  int L = blockIdx.x;
  f32x4 acc[4][4];
#pragma unroll
  for (int i = 0; i < 4; ++i)
#pragma unroll
    for (int j = 0; j < 4; ++j) acc[i][j] = (f32x4)(0.f);
  int lane = threadIdx.x & 63, wave = threadIdx.x >> 6;
  int wm = wave & 1, wn = wave >> 1, col = lane & 15, quad = lane >> 4;

  if (L < 1936) {
    int l = L, g1 = 0;
    if (l >= 968) { g1 = 1; l -= 968; }
    int rowSub = l & 7, t = l >> 3;
    int colIdx = t % 11, rowGroup = t / 11;
    int row0 = (rowGroup * 8 + rowSub) << 7;
    int col0 = colIdx << 7;
    const unsigned short* Am = g1 ? QVb : QKb;
    const unsigned short* Bm = g1 ? SVb : SKb;
    mfma_core((const short*)Am + (size_t)row0 * OUT_DIM, OUT_DIM, min(127, QROWS - 1 - row0),
              (const short*)Bm + (size_t)col0 * OUT_DIM, OUT_DIM, min(127, SROWS - 1 - col0),
              OUT_DIM, lds, acc);
    unsigned short* outp = g1 ? G1b : SCb;
    const float scl = g1 ? 1.0f : 0.029462782549439483f;  // 1/sqrt(1152)
#pragma unroll
    for (int i = 0; i < 4; ++i)
#pragma unroll
      for (int r = 0; r < 4; ++r) {
        int gr = row0 + wm * 64 + i * 16 + quad * 4 + r;
        if (gr >= QROWS) continue;
#pragma unroll
        for (int j = 0; j < 4; ++j) {
          int gc = col0 + wn * 64 + j * 16 + col;
          if (gc < SROWS) {
            int c = gc / 280;
            outp[(size_t)gr * AT_STRIDE + gc + c * 8] = f2bf(acc[i][j][r] * scl);
          }
        }
      }
  } else {
    int l = L - 1936;                 // 0..44: G2[c] = SV_c @ SV_c^T
    int c = l / 9, rem = l % 9;
    int i0 = (rem / 3) << 7, j0 = (rem % 3) << 7;
    const short* base = (const short*)SVb + (size_t)c * 280 * OUT_DIM;
    mfma_core(base + (size_t)i0 * OUT_DIM, OUT_DIM, min(127, 279 - i0),
              base + (size_t)j0 * OUT_DIM, OUT_DIM, min(127, 279 - j0),
              OUT_DIM, lds, acc);
    unsigned short* g2c = G2 + (size_t)c * KC * KC;
#pragma unroll
    for (int i = 0; i < 4; ++i)
#pragma unroll
      for (int r = 0; r < 4; ++r) {
        int gi = i0 + wm * 64 + i * 16 + quad * 4 + r;
        if (gi >= KC) continue;
#pragma unroll
        for (int j = 0; j < 4; ++j) {
          int gj = j0 + wn * 64 + j * 16 + col;
          if (gj < KC) g2c[(size_t)gi * KC + gj] = f2bf(acc[i][j][r]);
        }
      }
  }
}

// ---------------- k_attn: per-class softmax + T2 + T3 (= e^T G2 e / S^2) + out atomics ----------------
// One block per (64-row tile, class). 11200 = 175*64 exactly. attn stored as
// UNNORMALIZED e = exp(s - M) in LDS (bf16); T2 = (sum e*G1)/S; T3 = (e^T G2 e)/S^2.
__global__ __launch_bounds__(256) void k_attn(const unsigned short* __restrict__ SCb,
                                              const unsigned short* __restrict__ G1b,
                                              const unsigned short* __restrict__ G2,
                                              const float* __restrict__ qnorm,
                                              float* __restrict__ out) {
  __shared__ short attn[64 * ALD];
  __shared__ short Bs[4096];
  __shared__ float rowsum[64];
  __shared__ float T2n[64];
  __shared__ float Sarr[64];
  __shared__ float val[64];
  int r0 = blockIdx.x * 64, c = blockIdx.y;
  int tid = threadIdx.x;
  int lane = tid & 63, wave = tid >> 6;
  int col = lane & 15, quad = lane >> 4;

  // ---- phase 1: softmax numerators + T2 numerator (4 threads per row) ----
  int lr = tid >> 2, h = tid & 3;
  const unsigned short* ps = SCb + (size_t)(r0 + lr) * AT_STRIDE + c * KC;
  const unsigned short* pg = G1b + (size_t)(r0 + lr) * AT_STRIDE + c * KC;
  short8 sv[9];
  float mx = -INFINITY;
#pragma unroll
  for (int i = 0; i < 9; ++i) {
    int v = h * 9 + i;
    if (v < 35) {
      sv[i] = *(const short8*)(ps + v * 8);
#pragma unroll
      for (int j = 0; j < 8; ++j) mx = fmaxf(mx, bf2f((unsigned short)sv[i][j]));
    }
  }
  mx = fmaxf(mx, __shfl_xor(mx, 1));
  mx = fmaxf(mx, __shfl_xor(mx, 2));
  float sum = 0.f, t2 = 0.f;
#pragma unroll
  for (int i = 0; i < 9; ++i) {
    int v = h * 9 + i;
    if (v < 35) {
      short8 gv8 = *(const short8*)(pg + v * 8);
      short8 e8;
#pragma unroll
      for (int j = 0; j < 8; ++j) {
        float e = __expf(bf2f((unsigned short)sv[i][j]) - mx);
        sum += e;
        t2 += e * bf2f((unsigned short)gv8[j]);
        e8[j] = (short)f2bf(e);
      }
      *(short8*)(attn + lr * ALD + v * 8) = e8;
    } else {
      *(short8*)(attn + lr * ALD + v * 8) = (short8)0;   // zero class pads
    }
  }
  sum += __shfl_xor(sum, 1); sum += __shfl_xor(sum, 2);
  t2 += __shfl_xor(t2, 1); t2 += __shfl_xor(t2, 2);
  if (h == 0) { Sarr[lr] = sum; T2n[lr] = t2; }
  if (tid < 64) rowsum[tid] = 0.f;
  __syncthreads();

  // ---- phase 2: B2 = e @ G2_c, fused rowdot e^T G2 e ----
  const unsigned short* G2c = G2 + (size_t)c * KC * KC;
  float part[4][4] = {};
  for (int j0 = 0; j0 < KC; j0 += 128) {
    int maxB = KC - 1 - j0;
    f32x4 acc[4][2];
#pragma unroll
    for (int i = 0; i < 4; ++i) { acc[i][0] = (f32x4)(0.f); acc[i][1] = (f32x4)(0.f); }
    bool active = (wave * 32) <= maxB;
    for (int k0 = 0; k0 < KC; k0 += 32) {
      int s = tid, row = s >> 2, off = (s & 3) * 8;
      gll16(G2c + (size_t)(j0 + min(row, maxB)) * KC + k0 + off, Bs + s * 8);
      s = tid + 256; row = s >> 2; off = (s & 3) * 8;
      gll16(G2c + (size_t)(j0 + min(row, maxB)) * KC + k0 + off, Bs + s * 8);
      __syncthreads();
      if (active) {
        short8 af[4], bf[2];
#pragma unroll
        for (int i = 0; i < 4; ++i)
          af[i] = *(const short8*)(attn + (i * 16 + col) * ALD + k0 + quad * 8);
#pragma unroll
        for (int j = 0; j < 2; ++j)
          bf[j] = *(const short8*)(Bs + (wave * 32 + j * 16 + col) * 32 + quad * 8);
#pragma unroll
        for (int i = 0; i < 4; ++i)
#pragma unroll
          for (int j = 0; j < 2; ++j)
            acc[i][j] = __builtin_amdgcn_mfma_f32_16x16x32_bf16(af[i], bf[j], acc[i][j], 0, 0, 0);
      }
      __syncthreads();
    }
    if (active) {
#pragma unroll
      for (int i = 0; i < 4; ++i)
#pragma unroll
        for (int r = 0; r < 4; ++r) {
          int rl = i * 16 + quad * 4 + r;
#pragma unroll
          for (int j = 0; j < 2; ++j) {
            int gj = j0 + wave * 32 + j * 16 + col;
            if (gj < KC)
              part[i][r] += bf2f((unsigned short)attn[rl * ALD + gj]) * acc[i][j][r];
          }
        }
    }
  }
#pragma unroll
  for (int i = 0; i < 4; ++i)
#pragma unroll
    for (int r = 0; r < 4; ++r) {
      float s = part[i][r];
      s += __shfl_xor(s, 1); s += __shfl_xor(s, 2);
      s += __shfl_xor(s, 4); s += __shfl_xor(s, 8);
      if (col == 0) atomicAdd(&rowsum[i * 16 + quad * 4 + r], s);
    }
  __syncthreads();

  // ---- phase 3: per-row distance term, per-query reduce, out atomic ----
  if (tid < 64) {
    float S = Sarr[tid];
    float invS = 1.f / S;
    val[tid] = qnorm[r0 + tid] - 2.f * T2n[tid] * invS + rowsum[tid] * invS * invS;
  }
  __syncthreads();
  if (tid < 3) {
    int q = r0 / NTUP + tid;
    int lo = max(q * NTUP, r0), hi = min(q * NTUP + NTUP, r0 + 64);
    if (lo < hi && q < NQ) {
      float s = 0.f;
      for (int r = lo; r < hi; ++r) s += val[r - r0];
      atomicAdd(&out[q * WAY + c], -s * (1.f / NTUP));
    }
  }
}

// ---------------- launch ----------------
extern "C" void kernel_launch(void* const* d_in, const int* in_sizes, int n_in,
                              void* d_out, int out_size, void* d_ws, size_t ws_size,
                              hipStream_t stream) {
  const float* support = (const float*)d_in[0];
  const int* labels = (const int*)d_in[1];
  const float* queries = (const float*)d_in[2];
  const float* Wk = (const float*)d_in[3];
  const float* bk = (const float*)d_in[4];
  const float* Wv = (const float*)d_in[5];
  const float* bv = (const float*)d_in[6];
  const float* ln_g = (const float*)d_in[7];
  const float* ln_b = (const float*)d_in[8];
  float* out = (float*)d_out;
  char* w8 = (char*)d_ws;

  unsigned short* APb = (unsigned short*)(w8 + APB_OFF);
  unsigned short* WT = (unsigned short*)(w8 + WT_OFF);
  unsigned short* Pb = (unsigned short*)(w8 + PB_OFF);
  unsigned short* QKb = (unsigned short*)(w8 + QKB_OFF);
  unsigned short* SKb = (unsigned short*)(w8 + SKB_OFF);
  unsigned short* QVb = (unsigned short*)(w8 + QVB_OFF);
  unsigned short* SVb = (unsigned short*)(w8 + SVB_OFF);
  unsigned short* G2 = (unsigned short*)(w8 + G2_OFF);
  unsigned short* SCb = (unsigned short*)(w8 + SCB_OFF);
  unsigned short* G1b = (unsigned short*)(w8 + G1B_OFF);
  float* QNORM = (float*)(w8 + QNORM_OFF);
  int* RANK = (int*)(w8 + RANK_OFF);

  k_pre<<<dim3(NFRAMES + 13824 + 1), dim3(256), 0, stream>>>(support, queries, Wk, Wv,
                                                             labels, APb, WT, RANK, out);
  k_gemm1<<<dim3(54, 15), dim3(256), 0, stream>>>(APb, WT, Pb);
  k_combine<<<dim3(225, 2), dim3(256), 0, stream>>>(Pb, bk, bv, ln_g, ln_b, RANK,
                                                    SKb, QKb, SVb, QVb, QNORM);
  k_rowgemm<<<dim3(1981), dim3(256), 0, stream>>>(QKb, SKb, QVb, SVb, SCb, G1b, G2);
  k_attn<<<dim3(175, 5), dim3(256), 0, stream>>>(SCb, G1b, G2, QNORM, out);
}